// Round 9
// baseline (928.083 us; speedup 1.0000x reference)
//
#include <hip/hip_runtime.h>

typedef unsigned short u16;
typedef unsigned int u32;
typedef __attribute__((ext_vector_type(8))) u16 u16x8;
typedef __attribute__((ext_vector_type(8))) __bf16 bf16x8;
typedef __attribute__((ext_vector_type(4))) float f32x4;

__device__ __forceinline__ float b2f(u16 u){ return __uint_as_float(((u32)u)<<16); }
__device__ __forceinline__ u16 f2b(float f){
  u32 b = __float_as_uint(f);
  return (u16)((b + 0x7fffu + ((b>>16)&1u))>>16);
}
__device__ __forceinline__ void gload16(const void* g, void* l){
  __builtin_amdgcn_global_load_lds((__attribute__((address_space(1))) void*)g,
                                   (__attribute__((address_space(3))) void*)l, 16, 0, 0);
}
__device__ __forceinline__ float wred_max(float v){
#pragma unroll
  for (int o=32;o>0;o>>=1) v = fmaxf(v, __shfl_xor(v,o));
  return v;
}
__device__ __forceinline__ float wred_sum(float v){
#pragma unroll
  for (int o=32;o>0;o>>=1) v += __shfl_xor(v,o);
  return v;
}

// ---- fused preprocessing: cast x -> bf16 | weight transposes | agent qkv ----
// grid 6384 x 256: [0,2048) cast, [2048,6144) prep_w, [6144,6384) agent qkv
__global__ void k_pre(const float* __restrict__ x, const float* __restrict__ wvq,
                      const float* __restrict__ wvkv, const float* __restrict__ wout,
                      const float* __restrict__ waqkv,
                      u16* __restrict__ xb, u16* __restrict__ W1T,
                      u16* __restrict__ WoutT, float* __restrict__ aqkv){
  const int bid = blockIdx.x, tid = threadIdx.x;
  if (bid < 2048){
    const int stride = 2048*256;
    for (int i = bid*256 + tid; i < 8030720; i += stride){
      const float4* p = (const float4*)(x + (size_t)i*8);
      float4 a = p[0], b = p[1];
      u16x8 o;
      o[0]=f2b(a.x); o[1]=f2b(a.y); o[2]=f2b(a.z); o[3]=f2b(a.w);
      o[4]=f2b(b.x); o[5]=f2b(b.y); o[6]=f2b(b.z); o[7]=f2b(b.w);
      *(u16x8*)(xb + (size_t)i*8) = o;
    }
  } else if (bid < 6144){
    int id = (bid-2048)*256 + tid;   // [0, 1048576)
    if (id < 786432){
      int n = id >> 9, k = id & 511;
      float v = (n < 512) ? wvq[k*512 + n] : wvkv[k*1024 + (n-512)];
      W1T[id] = f2b(v);
    } else {
      int j = id - 786432;
      int n = j >> 9, k = j & 511;
      WoutT[j] = f2b(wout[k*512 + n]);
    }
  } else {
    int id = (bid-6144)*256 + tid;   // [0, 61440)
    int bt = id / 1536, c = id % 1536;
    const float* xr = x + (size_t)bt*3137*512;
    float s = 0.f;
    for (int k=0;k<512;k++) s += xr[k]*waqkv[k*1536+c];
    aqkv[id] = s;
  }
}

// ---- 128x128 GEMM, fragment-major LDS, 2-slot BK=32 ring, counted vmcnt ----
// A: MxK bf16 row-major, BT: NxK bf16 row-major. C = A * BT^T.
// LDS slot = A 8 tiles x 1KB | B 8 tiles x 1KB (16KB); tile t holds rows
// [16t,16t+16): lane l <- A[row=(l&15)][kbytes=(l>>4)*16]. Every ds_read_b128
// is uniform_base + lane*16: 0 bank conflicts, no per-read address math.
// Per slot: STAGE(s+1) -> vmcnt(4) -> barrier -> 8 ds_read -> lgkm(0) ->
// 16 MFMA (setprio) -> barrier. vmcnt never drains mid-loop (T4); latency
// hiding comes from 4 independent blocks/CU (32KB LDS, launch_bounds(256,4)).
// vmcnt ledger: at gate, outstanding = slot s (4) + slot s+1 (4 new) ->
// vmcnt(4) proves s. End barrier: all waves consumed s before STAGE(s+2)
// overwrites it. Epilogue: plain stores (nt measured 2x write amp, r4).
template<int FOUT>
__global__ __launch_bounds__(256, 4) void k_gemm128(
    const u16* __restrict__ A, const u16* __restrict__ BT,
    int M, int N, int K, int NX,
    u16* __restrict__ Cb, float* __restrict__ Cf, const float* __restrict__ bias)
{
  __shared__ __align__(16) char Ls[2][16384];
  const int tid = threadIdx.x;
  const int wid = tid >> 6, lane = tid & 63;
  // XCD-bijective swizzle (m204), n-fast work order (A-panel L2 residency)
  const int nwg = gridDim.x, orig = blockIdx.x;
  const int q8 = nwg >> 3, r8 = nwg & 7;
  const int xc = orig & 7, sl = orig >> 3;
  const int work = (xc < r8 ? xc*(q8+1) : r8*(q8+1) + (xc-r8)*q8) + sl;
  const int m0 = (work / NX) * 128, n0 = (work % NX) * 128;
  const size_t K2 = (size_t)K * 2;
  const char* Ab = (const char*)A;
  const char* Bb = (const char*)BT;
  size_t asrc[2], bsrc[2];
  const int ad0 = (2*wid)*1024, ad1 = (2*wid+1)*1024;   // wave-uniform LDS dests
#pragma unroll
  for (int i=0;i<2;i++){
    int row = (2*wid + i)*16 + (lane & 15);
    int koff = (lane >> 4) << 4;
    int ra = m0 + row; if (ra >= M) ra = M-1;   // clamp partial last M-tile
    asrc[i] = (size_t)ra*K2 + koff;
    bsrc[i] = (size_t)(n0 + row)*K2 + koff;     // N multiple of 128
  }
#define STAGE(s2, ks) { \
    size_t ko = (size_t)(ks) * 64; \
    gload16(Ab + asrc[0] + ko, Ls[s2] + ad0); \
    gload16(Ab + asrc[1] + ko, Ls[s2] + ad1); \
    gload16(Bb + bsrc[0] + ko, Ls[s2] + 8192 + ad0); \
    gload16(Bb + bsrc[1] + ko, Ls[s2] + 8192 + ad1); }

  f32x4 acc[4][4] = {};
  const int awb = (wid>>1)*4096;            // wave's 4 A-tiles
  const int bwb = 8192 + (wid&1)*4096;      // wave's 4 B-tiles
  const int NS = K >> 5;
  STAGE(0,0)
  for (int s = 0; s < NS; ++s){
    if (s+1 < NS){
      STAGE((s+1)&1, s+1)
      asm volatile("s_waitcnt vmcnt(4)" ::: "memory");
    } else {
      asm volatile("s_waitcnt vmcnt(0)" ::: "memory");
    }
    __builtin_amdgcn_s_barrier();           // slot s ready for all waves
    __builtin_amdgcn_sched_barrier(0);
    const char* base = Ls[s&1];
    bf16x8 af[4], bf[4];
#pragma unroll
    for (int i=0;i<4;i++) af[i] = *(const bf16x8*)(base + awb + i*1024 + lane*16);
#pragma unroll
    for (int i=0;i<4;i++) bf[i] = *(const bf16x8*)(base + bwb + i*1024 + lane*16);
    __builtin_amdgcn_sched_barrier(0);
    asm volatile("s_waitcnt lgkmcnt(0)" ::: "memory");
    __builtin_amdgcn_sched_barrier(0);
    __builtin_amdgcn_s_setprio(1);
#pragma unroll
    for (int mr=0;mr<4;mr++)
#pragma unroll
      for (int nc=0;nc<4;nc++)
        acc[mr][nc] = __builtin_amdgcn_mfma_f32_16x16x32_bf16(af[mr], bf[nc], acc[mr][nc], 0,0,0);
    __builtin_amdgcn_s_setprio(0);
    __builtin_amdgcn_sched_barrier(0);
    __builtin_amdgcn_s_barrier();           // slot s consumed by all waves
  }
#undef STAGE
  const int wm = (wid>>1)*64, wn = (wid&1)*64;
  if (m0 + 128 <= M){
#pragma unroll
    for (int mr=0;mr<4;mr++){
#pragma unroll
      for (int nc=0;nc<4;nc++){
#pragma unroll
        for (int rg=0;rg<4;rg++){
          int row = m0 + wm + mr*16 + ((lane>>4)<<2) + rg;
          int col = n0 + wn + nc*16 + (lane&15);
          float v = acc[mr][nc][rg];
          if (FOUT) Cf[(size_t)row*N + col] = v + bias[col];
          else      Cb[(size_t)row*N + col] = f2b(v);
        }
      }
    }
  } else {
#pragma unroll
    for (int mr=0;mr<4;mr++){
#pragma unroll
      for (int nc=0;nc<4;nc++){
#pragma unroll
        for (int rg=0;rg<4;rg++){
          int row = m0 + wm + mr*16 + ((lane>>4)<<2) + rg;
          int col = n0 + wn + nc*16 + (lane&15);
          if (row < M){
            float v = acc[mr][nc][rg];
            if (FOUT) Cf[(size_t)row*N + col] = v + bias[col];
            else      Cb[(size_t)row*N + col] = f2b(v);
          }
        }
      }
    }
  }
}

// ---------------- agent attention: softmax over 15680 keys, split-K=16 ----------------
// grid 1024 = (bh 64) x (split 16); block 320 = 5 waves (one per query t)
__global__ __launch_bounds__(320) void k_attn_agent(
    const u16* __restrict__ out1, const float* __restrict__ aqkv,
    float* __restrict__ pm, float* __restrict__ pl, float* __restrict__ pacc)
{
  __shared__ __align__(16) char Ksm[16384];   // 128 keys x 64 bf16, XOR-swizzled
  __shared__ __align__(16) char Vsm[16384];
  const int bid = blockIdx.x;
  const int sp = bid & 15, bh = bid >> 4, b = bh >> 3, h = bh & 7;
  const int tid = threadIdx.x, wid = tid >> 6, lane = tid & 63;
  const int q = wid;                           // query t index 0..4
  float qreg[64];
  {
    const float* ap = aqkv + ((size_t)(b*5+q)*1536 + h*64);
#pragma unroll
    for (int d=0; d<64; d++) qreg[d] = ap[d];
  }
  float m = -1e30f, l = 0.f;
  float acc[8] = {0,0,0,0,0,0,0,0};
  const int g0 = sp * 980;                     // 15680/16 keys per split
  for (int c = 0; c < 8; c++){                 // 7*128 + 84 = 980
    for (int idx = tid; idx < 2048; idx += 320){
      int arr = idx >> 10, rem = idx & 1023;
      int r = rem >> 3, seg = rem & 7;
      int loc = c*128 + r; if (loc > 979) loc = 979;
      int gk = g0 + loc;
      int tk = gk / 3136, nv = gk - tk*3136;
      size_t grow = (size_t)((b*5+tk)*3137 + 1 + nv)*1536 + (arr ? 1024 : 512) + h*64 + seg*8;
      u16x8 v = *(const u16x8*)(out1 + grow);
      char* dst = arr ? Vsm : Ksm;
      *(u16x8*)(dst + r*128 + ((seg*16) ^ ((r&7)<<4))) = v;
    }
    __syncthreads();
    // dot: lane owns keys (lane) and (64+lane)
    float s0 = 0.f, s1 = 0.f;
#pragma unroll
    for (int seg=0; seg<8; seg++){
      const int r0 = lane, r1 = 64 + lane;
      u16x8 k0 = *(const u16x8*)(Ksm + r0*128 + ((seg*16) ^ ((r0&7)<<4)));
      u16x8 k1 = *(const u16x8*)(Ksm + r1*128 + ((seg*16) ^ ((r1&7)<<4)));
#pragma unroll
      for (int j=0;j<8;j++){
        s0 += qreg[seg*8+j]*b2f(k0[j]);
        s1 += qreg[seg*8+j]*b2f(k1[j]);
      }
    }
    s0 *= 0.125f; s1 *= 0.125f;
    const int locbase = c*128;
    if (locbase + lane >= 980)      s0 = -1e30f;
    if (locbase + 64 + lane >= 980) s1 = -1e30f;
    float cmax = wred_max(fmaxf(s0, s1));
    float mn = fmaxf(m, cmax);
    float resc = __expf(m - mn);
    float p0 = (s0 > -1e29f) ? __expf(s0 - mn) : 0.f;
    float p1 = (s1 > -1e29f) ? __expf(s1 - mn) : 0.f;
    l = l*resc + wred_sum(p0 + p1);
#pragma unroll
    for (int j=0;j<8;j++) acc[j] *= resc;
    // PV: lane = (key-group g = lane>>3) x (d-chunk cc = lane&7), conflict-free
    const int g = lane >> 3, cc = lane & 7;
#pragma unroll
    for (int i=0;i<16;i++){
      int k = i*8 + g;
      u16x8 vv = *(const u16x8*)(Vsm + k*128 + ((cc*16) ^ ((k&7)<<4)));
      float p = (i < 8) ? __shfl(p0, k) : __shfl(p1, k-64);
#pragma unroll
      for (int j=0;j<8;j++) acc[j] += p*b2f(vv[j]);
    }
    m = mn;
    __syncthreads();
  }
  // reduce partial acc across the 8 key-groups
#pragma unroll
  for (int j=0;j<8;j++){
    float v = acc[j];
    v += __shfl_xor(v, 8); v += __shfl_xor(v, 16); v += __shfl_xor(v, 32);
    acc[j] = v;
  }
  const int base = (bh*16 + sp)*5 + q;
  if (lane == 0){ pm[base] = m; pl[base] = l; }
  if (lane < 8){
    float* pa = pacc + (size_t)base*64 + lane*8;
#pragma unroll
    for (int j=0;j<8;j++) pa[j] = acc[j];
  }
}

// ---- frame attention (k=5)+mask -> v rows of IN; fused split-K combine -> a rows ----
// grid 4000 x 256: [0,3920) frame (490 per b), [3920,4000) combine (4 per block)
__global__ __launch_bounds__(256) void k_attn_frame(
    const u16* __restrict__ out1, const float* __restrict__ aqkv,
    const float* __restrict__ mask, const float* __restrict__ pm,
    const float* __restrict__ pl, const float* __restrict__ pacc,
    u16* __restrict__ IN)
{
  const int bid = blockIdx.x, tid = threadIdx.x;
  if (bid < 3920){
    __shared__ float Ka[5][8][68];
    __shared__ float Va[5][8][68];
    const int b = bid / 490, bx = bid % 490;
    for (int i = tid; i < 2560; i += 256){
      int t = i >> 9, rem = i & 511, hh = rem >> 6, d = rem & 63;
      const float* src = aqkv + (size_t)(b*5+t)*1536;
      Ka[t][hh][d] = src[512 + hh*64 + d];
      Va[t][hh][d] = src[1024 + hh*64 + d];
    }
    __syncthreads();
    const int task = bx*256 + tid;   // 0..125439
    const int h = task & 7, rl = task >> 3;
    const int f = rl / 3136, nv = rl - f*3136;
    const int bt = b*5 + f;
    const size_t r1 = (size_t)bt*3137 + 1 + nv;
    const u16* qp = out1 + r1*1536 + h*64;   // vq slice
    float qf[64];
#pragma unroll
    for (int sg=0; sg<8; sg++){
      u16x8 v = *(const u16x8*)(qp + sg*8);
#pragma unroll
      for (int j=0;j<8;j++) qf[sg*8+j] = b2f(v[j]);
    }
    float sd[5];
#pragma unroll
    for (int t=0;t<5;t++){
      float s = 0.f;
#pragma unroll
      for (int d=0;d<64;d++) s += qf[d]*Ka[t][h][d];
      sd[t] = s*0.125f;
    }
    float mx = sd[0];
#pragma unroll
    for (int t=1;t<5;t++) mx = fmaxf(mx, sd[t]);
    float p[5], ps = 0.f;
#pragma unroll
    for (int t=0;t<5;t++){ p[t] = __expf(sd[t]-mx); ps += p[t]; }
    const float mv = mask[(size_t)bt*3136 + nv] / ps;   // fold mask into normalizer
    u16* op = IN + r1*512 + h*64;
#pragma unroll
    for (int sg=0; sg<8; sg++){
      u16x8 o;
#pragma unroll
      for (int j=0;j<8;j++){
        const int d = sg*8+j;
        float v = 0.f;
#pragma unroll
        for (int t=0;t<5;t++) v += p[t]*Va[t][h][d];
        o[j] = f2b(v*mv);
      }
      *(u16x8*)(op + sg*8) = o;
    }
  } else {
    // combine: 4 (b,h,q) tasks per block, 64 lanes each over d
    const int id = (bid - 3920)*4 + (tid >> 6);   // [0,320)
    const int d = tid & 63;
    const int q = id % 5, t2 = id / 5;
    const int h = t2 & 7, b = t2 >> 3;
    const int bh = b*8 + h;
    float ms = -1e30f;
#pragma unroll
    for (int s2=0;s2<16;s2++) ms = fmaxf(ms, pm[(bh*16+s2)*5+q]);
    float L = 0.f, o = 0.f;
#pragma unroll
    for (int s2=0;s2<16;s2++){
      int base = (bh*16+s2)*5+q;
      float w = __expf(pm[base]-ms);
      L += w*pl[base];
      o += w*pacc[(size_t)base*64 + d];
    }
    IN[(size_t)(b*5+q)*3137*512 + h*64 + d] = f2b(o / L);
  }
}

extern "C" void kernel_launch(void* const* d_in, const int* in_sizes, int n_in,
                              void* d_out, int out_size, void* d_ws, size_t ws_size,
                              hipStream_t stream)
{
  const float* x      = (const float*)d_in[0];
  const float* mask   = (const float*)d_in[1];
  const float* w_vq   = (const float*)d_in[2];
  const float* w_vkv  = (const float*)d_in[3];
  const float* w_aqkv = (const float*)d_in[4];
  const float* w_out  = (const float*)d_in[5];
  const float* b_out  = (const float*)d_in[6];
  float* out = (float*)d_out;
  char* ws = (char*)d_ws;

  constexpr size_t MR = 125480;                          // 40*3137
  constexpr size_t OFF_XB   = 0;                         // M x 512 bf16 (later reused as IN)
  constexpr size_t OFF_OUT1 = OFF_XB + MR*512*2;         // M x 1536 bf16 [vq|vk|vv]
  constexpr size_t OFF_W1T  = OFF_OUT1 + MR*1536*2;      // 1536x512 bf16
  constexpr size_t OFF_WOT  = OFF_W1T + 1536*512*2;      // 512x512 bf16
  constexpr size_t OFF_AQKV = OFF_WOT + 512*512*2;       // 40x1536 f32
  constexpr size_t OFF_PM   = OFF_AQKV + 40*1536*4;      // 5120 f32
  constexpr size_t OFF_PL   = OFF_PM + 5120*4;           // 5120 f32
  constexpr size_t OFF_PACC = OFF_PL + 5120*4;           // 5120*64 f32

  u16* Xb     = (u16*)(ws + OFF_XB);
  u16* out1   = (u16*)(ws + OFF_OUT1);
  u16* W1T    = (u16*)(ws + OFF_W1T);
  u16* WoutT  = (u16*)(ws + OFF_WOT);
  float* aqkv = (float*)(ws + OFF_AQKV);
  float* pm   = (float*)(ws + OFF_PM);
  float* pl   = (float*)(ws + OFF_PL);
  float* pacc = (float*)(ws + OFF_PACC);

  k_pre<<<6384, 256, 0, stream>>>(x, w_vq, w_vkv, w_out, w_aqkv, Xb, W1T, WoutT, aqkv);
  k_gemm128<0><<<11772, 256, 0, stream>>>(Xb, W1T, (int)MR, 1536, 512, 12, out1, nullptr, nullptr);
  k_attn_agent<<<1024, 320, 0, stream>>>(out1, aqkv, pm, pl, pacc);
  k_attn_frame<<<4000, 256, 0, stream>>>(out1, aqkv, mask, pm, pl, pacc, Xb);
  k_gemm128<1><<<3924, 256, 0, stream>>>(Xb, WoutT, (int)MR, 512, 512, 4, nullptr, out, b_out);
}

// Round 10
// 905.788 us; speedup vs baseline: 1.0246x; 1.0246x over previous
//
#include <hip/hip_runtime.h>

typedef unsigned short u16;
typedef unsigned int u32;
typedef __attribute__((ext_vector_type(8))) u16 u16x8;
typedef __attribute__((ext_vector_type(8))) __bf16 bf16x8;
typedef __attribute__((ext_vector_type(4))) float f32x4;

__device__ __forceinline__ float b2f(u16 u){ return __uint_as_float(((u32)u)<<16); }
__device__ __forceinline__ u16 f2b(float f){
  u32 b = __float_as_uint(f);
  return (u16)((b + 0x7fffu + ((b>>16)&1u))>>16);
}
__device__ __forceinline__ void gload16(const void* g, void* l){
  __builtin_amdgcn_global_load_lds((__attribute__((address_space(1))) void*)g,
                                   (__attribute__((address_space(3))) void*)l, 16, 0, 0);
}
__device__ __forceinline__ float wred_max(float v){
#pragma unroll
  for (int o=32;o>0;o>>=1) v = fmaxf(v, __shfl_xor(v,o));
  return v;
}
__device__ __forceinline__ float wred_sum(float v){
#pragma unroll
  for (int o=32;o>0;o>>=1) v += __shfl_xor(v,o);
  return v;
}

// ---- fused preprocessing: cast x -> bf16 | weight transposes | agent qkv ----
// grid 6384 x 256: [0,2048) cast, [2048,6144) prep_w, [6144,6384) agent qkv
__global__ void k_pre(const float* __restrict__ x, const float* __restrict__ wvq,
                      const float* __restrict__ wvkv, const float* __restrict__ wout,
                      const float* __restrict__ waqkv,
                      u16* __restrict__ xb, u16* __restrict__ W1T,
                      u16* __restrict__ WoutT, float* __restrict__ aqkv){
  const int bid = blockIdx.x, tid = threadIdx.x;
  if (bid < 2048){
    const int stride = 2048*256;
    for (int i = bid*256 + tid; i < 8030720; i += stride){
      const float4* p = (const float4*)(x + (size_t)i*8);
      float4 a = p[0], b = p[1];
      u16x8 o;
      o[0]=f2b(a.x); o[1]=f2b(a.y); o[2]=f2b(a.z); o[3]=f2b(a.w);
      o[4]=f2b(b.x); o[5]=f2b(b.y); o[6]=f2b(b.z); o[7]=f2b(b.w);
      *(u16x8*)(xb + (size_t)i*8) = o;
    }
  } else if (bid < 6144){
    int id = (bid-2048)*256 + tid;   // [0, 1048576)
    if (id < 786432){
      int n = id >> 9, k = id & 511;
      float v = (n < 512) ? wvq[k*512 + n] : wvkv[k*1024 + (n-512)];
      W1T[id] = f2b(v);
    } else {
      int j = id - 786432;
      int n = j >> 9, k = j & 511;
      WoutT[j] = f2b(wout[k*512 + n]);
    }
  } else {
    int id = (bid-6144)*256 + tid;   // [0, 61440)
    int bt = id / 1536, c = id % 1536;
    const float* xr = x + (size_t)bt*3137*512;
    float s = 0.f;
    for (int k=0;k<512;k++) s += xr[k]*waqkv[k*1536+c];
    aqkv[id] = s;
  }
}

// ---------------- 128x128x64 bf16 MFMA GEMM (round-6 proven loop) ----------------
// A: MxK bf16 row-major, BT: NxK bf16 row-major.
// FOUT=0: GEMM1. n-tiles with n0<512 (vq cols) -> FUSED frame attention in the
//   epilogue (softmax over T=5 using ak/av staged to LDS), masked, written to IN.
//   n-tiles n0>=512 -> plain bf16 write to out1kv at col-512 (stride 1024).
// FOUT=1: GEMM2, f32 + bias to Cf.
// XCD-bijective grid swizzle (verified: FETCH 512->81MB). Plain stores only
// (nt measured 2x write amplification on partial-line stores -- round 4).
template<int FOUT>
__global__ __launch_bounds__(256) void k_gemm_bt(
    const u16* __restrict__ A, const u16* __restrict__ BT,
    int M, int N, int K, int NX,
    u16* __restrict__ Cb, float* __restrict__ Cf, const float* __restrict__ bias,
    u16* __restrict__ IN, const float* __restrict__ aqkv,
    const float* __restrict__ mask)
{
  __shared__ __align__(16) char Asm[128*64*2];
  __shared__ __align__(16) char Bsm[128*64*2];
  const int tid = threadIdx.x;
  const int wid = tid >> 6, lane = tid & 63;
  const int nwg = gridDim.x, orig = blockIdx.x;
  const int q8 = nwg >> 3, r8 = nwg & 7;
  const int xc = orig & 7, sl = orig >> 3;
  const int work = (xc < r8 ? xc*(q8+1) : r8*(q8+1) + (xc-r8)*q8) + sl;
  const int m0 = (work / NX) * 128, n0 = (work % NX) * 128;
  const char* Ab = (const char*)A;
  const char* Bb = (const char*)BT;
  size_t aoff[4], boff[4];
  int ldsoff[4];
#pragma unroll
  for (int i=0;i<4;i++){
    int L = i*4096 + wid*1024 + lane*16;       // linear LDS byte this lane fills
    int r = L >> 7;                            // tile row (stride 128B)
    int cb = (L ^ ((r&7)<<4)) & 127;           // inverse-swizzled source col byte
    ldsoff[i] = i*4096 + wid*1024;             // wave-uniform LDS dest base
    int ra = m0 + r; if (ra >= M) ra = M-1;    // clamp partial last tile
    aoff[i] = (size_t)ra*(size_t)(K*2) + cb;
    boff[i] = (size_t)(n0 + r)*(size_t)(K*2) + cb;
  }
  f32x4 acc[4][4] = {};
  const int wm = (wid>>1)*64, wn = (wid&1)*64;

  for (int k0 = 0; k0 < K; k0 += 64){
#pragma unroll
    for (int i=0;i<4;i++){
      gload16(Ab + aoff[i] + k0*2, Asm + ldsoff[i]);
      gload16(Bb + boff[i] + k0*2, Bsm + ldsoff[i]);
    }
    __syncthreads();
#pragma unroll
    for (int kk=0;kk<2;kk++){
      const int cb = kk*64 + ((lane>>4)<<4);
      bf16x8 af[4], bfr[4];
#pragma unroll
      for (int mr=0;mr<4;mr++){
        int r = wm + mr*16 + (lane&15);
        af[mr] = *(const bf16x8*)(Asm + r*128 + (cb ^ ((r&7)<<4)));
      }
#pragma unroll
      for (int nc=0;nc<4;nc++){
        int r = wn + nc*16 + (lane&15);
        bfr[nc] = *(const bf16x8*)(Bsm + r*128 + (cb ^ ((r&7)<<4)));
      }
#pragma unroll
      for (int mr=0;mr<4;mr++)
#pragma unroll
        for (int nc=0;nc<4;nc++)
          acc[mr][nc] = __builtin_amdgcn_mfma_f32_16x16x32_bf16(af[mr], bfr[nc], acc[mr][nc], 0,0,0);
    }
    __syncthreads();
  }

  if (FOUT == 0 && n0 < 512){
    // ---- fused frame attention: acc holds vq for rows x head (n0/64 + (wid&1)) ----
    float* akL = (float*)Asm;            // [bi2][t5][hh2][d64] = 1280 f32
    float* avL = (float*)(Asm + 5120);
    const int b0 = m0 / 15685;           // 15685 = 5*3137 rows per b
    const int h0 = n0 >> 6;
    for (int i = tid; i < 1280; i += 256){
      int bi = i / 640, rem = i - bi*640;
      int t = rem >> 7, rem2 = rem & 127;
      int hh = rem2 >> 6, d = rem2 & 63;
      int bsel = b0 + bi; if (bsel > 7) bsel = 7;
      const float* src = aqkv + (size_t)(bsel*5 + t)*1536 + (h0+hh)*64 + d;
      akL[i] = src[512];
      avL[i] = src[1024];
    }
    __syncthreads();
    const int ln = lane & 15, lq = lane >> 4;
    const int hh = wid & 1;
    const int thr1 = (b0+1)*15685;
#pragma unroll
    for (int mr=0;mr<4;mr++){
#pragma unroll
      for (int rg=0;rg<4;rg++){
        const int row = m0 + wm + mr*16 + lq*4 + rg;
        const int bi = (row >= thr1) ? 1 : 0;
        float pt[5];
#pragma unroll
        for (int t=0;t<5;t++){
          const float* ak = akL + ((bi*5+t)*2 + hh)*64 + ln;
          pt[t] = acc[mr][0][rg]*ak[0]  + acc[mr][1][rg]*ak[16]
                + acc[mr][2][rg]*ak[32] + acc[mr][3][rg]*ak[48];
        }
#pragma unroll
        for (int off=1; off<16; off<<=1){
#pragma unroll
          for (int t=0;t<5;t++) pt[t] += __shfl_xor(pt[t], off);
        }
        float mx = fmaxf(fmaxf(fmaxf(pt[0],pt[1]),fmaxf(pt[2],pt[3])),pt[4]);
        float ps = 0.f;
#pragma unroll
        for (int t=0;t<5;t++){ pt[t] = __expf((pt[t]-mx)*0.125f); ps += pt[t]; }
        const int bt = row / 3137;
        const int j  = row - bt*3137;
        const float mvv = (j > 0 && row < M) ? mask[(size_t)bt*3136 + (j-1)] : 0.f;
        const float mv = mvv / ps;   // agent rows (j==0) get 0; combine overwrites
        if (row < M){
          u16* op = IN + (size_t)row*512 + (h0+hh)*64 + ln;
#pragma unroll
          for (int nc=0;nc<4;nc++){
            const float* av = avL + ((bi*5)*2 + hh)*64 + nc*16 + ln;
            float o = pt[0]*av[0] + pt[1]*av[128] + pt[2]*av[256]
                    + pt[3]*av[384] + pt[4]*av[512];   // t stride = 2*64
            op[nc*16] = f2b(o*mv);
          }
        }
      }
    }
  } else {
    // ---- plain epilogue ----
    const int cshift = (FOUT == 0) ? 512 : 0;   // out1kv starts at logical col 512
    const int NW = (FOUT == 0) ? 1024 : N;
    if (m0 + 128 <= M){
#pragma unroll
      for (int mr=0;mr<4;mr++){
#pragma unroll
        for (int nc=0;nc<4;nc++){
#pragma unroll
          for (int rg=0;rg<4;rg++){
            int row = m0 + wm + mr*16 + ((lane>>4)<<2) + rg;
            int col = n0 + wn + nc*16 + (lane&15) - cshift;
            float v = acc[mr][nc][rg];
            if (FOUT) Cf[(size_t)row*NW + col] = v + bias[col];
            else      Cb[(size_t)row*NW + col] = f2b(v);
          }
        }
      }
    } else {
#pragma unroll
      for (int mr=0;mr<4;mr++){
#pragma unroll
        for (int nc=0;nc<4;nc++){
#pragma unroll
          for (int rg=0;rg<4;rg++){
            int row = m0 + wm + mr*16 + ((lane>>4)<<2) + rg;
            int col = n0 + wn + nc*16 + (lane&15) - cshift;
            if (row < M){
              float v = acc[mr][nc][rg];
              if (FOUT) Cf[(size_t)row*NW + col] = v + bias[col];
              else      Cb[(size_t)row*NW + col] = f2b(v);
            }
          }
        }
      }
    }
  }
}

// ---------------- agent attention: softmax over 15680 keys, split-K=16 ----------------
// grid 1024 = (bh 64) x (split 16); block 320 = 5 waves (one per query t)
// out1kv layout: [row][1024] = [vk(512) | vv(512)]
__global__ __launch_bounds__(320) void k_attn_agent(
    const u16* __restrict__ out1, const float* __restrict__ aqkv,
    float* __restrict__ pm, float* __restrict__ pl, float* __restrict__ pacc)
{
  __shared__ __align__(16) char Ksm[16384];   // 128 keys x 64 bf16, XOR-swizzled
  __shared__ __align__(16) char Vsm[16384];
  const int bid = blockIdx.x;
  const int sp = bid & 15, bh = bid >> 4, b = bh >> 3, h = bh & 7;
  const int tid = threadIdx.x, wid = tid >> 6, lane = tid & 63;
  const int q = wid;                           // query t index 0..4
  float qreg[64];
  {
    const float* ap = aqkv + ((size_t)(b*5+q)*1536 + h*64);
#pragma unroll
    for (int d=0; d<64; d++) qreg[d] = ap[d];
  }
  float m = -1e30f, l = 0.f;
  float acc[8] = {0,0,0,0,0,0,0,0};
  const int g0 = sp * 980;                     // 15680/16 keys per split
  for (int c = 0; c < 8; c++){                 // 7*128 + 84 = 980
    for (int idx = tid; idx < 2048; idx += 320){
      int arr = idx >> 10, rem = idx & 1023;
      int r = rem >> 3, seg = rem & 7;
      int loc = c*128 + r; if (loc > 979) loc = 979;
      int gk = g0 + loc;
      int tk = gk / 3136, nv = gk - tk*3136;
      size_t grow = (size_t)((b*5+tk)*3137 + 1 + nv)*1024 + (arr ? 512 : 0) + h*64 + seg*8;
      u16x8 v = *(const u16x8*)(out1 + grow);
      char* dst = arr ? Vsm : Ksm;
      *(u16x8*)(dst + r*128 + ((seg*16) ^ ((r&7)<<4))) = v;
    }
    __syncthreads();
    float s0 = 0.f, s1 = 0.f;
#pragma unroll
    for (int seg=0; seg<8; seg++){
      const int r0 = lane, r1 = 64 + lane;
      u16x8 k0 = *(const u16x8*)(Ksm + r0*128 + ((seg*16) ^ ((r0&7)<<4)));
      u16x8 k1 = *(const u16x8*)(Ksm + r1*128 + ((seg*16) ^ ((r1&7)<<4)));
#pragma unroll
      for (int j=0;j<8;j++){
        s0 += qreg[seg*8+j]*b2f(k0[j]);
        s1 += qreg[seg*8+j]*b2f(k1[j]);
      }
    }
    s0 *= 0.125f; s1 *= 0.125f;
    const int locbase = c*128;
    if (locbase + lane >= 980)      s0 = -1e30f;
    if (locbase + 64 + lane >= 980) s1 = -1e30f;
    float cmax = wred_max(fmaxf(s0, s1));
    float mn = fmaxf(m, cmax);
    float resc = __expf(m - mn);
    float p0 = (s0 > -1e29f) ? __expf(s0 - mn) : 0.f;
    float p1 = (s1 > -1e29f) ? __expf(s1 - mn) : 0.f;
    l = l*resc + wred_sum(p0 + p1);
#pragma unroll
    for (int j=0;j<8;j++) acc[j] *= resc;
    const int g = lane >> 3, cc = lane & 7;
#pragma unroll
    for (int i=0;i<16;i++){
      int k = i*8 + g;
      u16x8 vv = *(const u16x8*)(Vsm + k*128 + ((cc*16) ^ ((k&7)<<4)));
      float p = (i < 8) ? __shfl(p0, k) : __shfl(p1, k-64);
#pragma unroll
      for (int j=0;j<8;j++) acc[j] += p*b2f(vv[j]);
    }
    m = mn;
    __syncthreads();
  }
#pragma unroll
  for (int j=0;j<8;j++){
    float v = acc[j];
    v += __shfl_xor(v, 8); v += __shfl_xor(v, 16); v += __shfl_xor(v, 32);
    acc[j] = v;
  }
  const int base = (bh*16 + sp)*5 + q;
  if (lane == 0){ pm[base] = m; pl[base] = l; }
  if (lane < 8){
    float* pa = pacc + (size_t)base*64 + lane*8;
#pragma unroll
    for (int j=0;j<8;j++) pa[j] = acc[j];
  }
}

// ---------------- combine split-K partials -> agent rows of IN ----------------
__global__ void k_combine(const float* __restrict__ pm, const float* __restrict__ pl,
                          const float* __restrict__ pacc, u16* __restrict__ IN)
{
  const int id = blockIdx.x;   // 320 = b*8h*5q
  const int q = id % 5, t2 = id / 5;
  const int h = t2 & 7, b = t2 >> 3;
  const int d = threadIdx.x;   // 64
  const int bh = b*8 + h;
  float ms = -1e30f;
#pragma unroll
  for (int s2=0;s2<16;s2++) ms = fmaxf(ms, pm[(bh*16+s2)*5+q]);
  float L = 0.f, o = 0.f;
#pragma unroll
  for (int s2=0;s2<16;s2++){
    int base = (bh*16+s2)*5+q;
    float w = __expf(pm[base]-ms);
    L += w*pl[base];
    o += w*pacc[(size_t)base*64 + d];
  }
  IN[(size_t)(b*5+q)*3137*512 + h*64 + d] = f2b(o / L);
}

extern "C" void kernel_launch(void* const* d_in, const int* in_sizes, int n_in,
                              void* d_out, int out_size, void* d_ws, size_t ws_size,
                              hipStream_t stream)
{
  const float* x      = (const float*)d_in[0];
  const float* mask   = (const float*)d_in[1];
  const float* w_vq   = (const float*)d_in[2];
  const float* w_vkv  = (const float*)d_in[3];
  const float* w_aqkv = (const float*)d_in[4];
  const float* w_out  = (const float*)d_in[5];
  const float* b_out  = (const float*)d_in[6];
  float* out = (float*)d_out;
  char* ws = (char*)d_ws;

  constexpr size_t MR = 125480;                          // 40*3137
  constexpr size_t OFF_XB   = 0;                         // M x 512 bf16 (GEMM1 A)
  constexpr size_t OFF_KV   = OFF_XB + MR*512*2;         // M x 1024 bf16 [vk|vv]
  constexpr size_t OFF_IN   = OFF_KV + MR*1024*2;        // M x 512 bf16 (GEMM2 A)
  constexpr size_t OFF_W1T  = OFF_IN + MR*512*2;         // 1536x512 bf16
  constexpr size_t OFF_WOT  = OFF_W1T + 1536*512*2;      // 512x512 bf16
  constexpr size_t OFF_AQKV = OFF_WOT + 512*512*2;       // 40x1536 f32
  constexpr size_t OFF_PM   = OFF_AQKV + 40*1536*4;      // 5120 f32
  constexpr size_t OFF_PL   = OFF_PM + 5120*4;           // 5120 f32
  constexpr size_t OFF_PACC = OFF_PL + 5120*4;           // 5120*64 f32

  u16* Xb     = (u16*)(ws + OFF_XB);
  u16* out1kv = (u16*)(ws + OFF_KV);
  u16* IN     = (u16*)(ws + OFF_IN);
  u16* W1T    = (u16*)(ws + OFF_W1T);
  u16* WoutT  = (u16*)(ws + OFF_WOT);
  float* aqkv = (float*)(ws + OFF_AQKV);
  float* pm   = (float*)(ws + OFF_PM);
  float* pl   = (float*)(ws + OFF_PL);
  float* pacc = (float*)(ws + OFF_PACC);

  k_pre<<<6384, 256, 0, stream>>>(x, w_vq, w_vkv, w_out, w_aqkv, Xb, W1T, WoutT, aqkv);
  k_gemm_bt<0><<<11772, 256, 0, stream>>>(Xb, W1T, (int)MR, 1536, 512, 12,
                                          out1kv, nullptr, nullptr, IN, aqkv, mask);
  k_attn_agent<<<1024, 320, 0, stream>>>(out1kv, aqkv, pm, pl, pacc);
  k_combine<<<320, 64, 0, stream>>>(pm, pl, pacc, IN);
  k_gemm_bt<1><<<3924, 256, 0, stream>>>(IN, WoutT, (int)MR, 512, 512, 4,
                                         nullptr, out, b_out, nullptr, nullptr, nullptr);
}

// Round 11
// 859.919 us; speedup vs baseline: 1.0793x; 1.0533x over previous
//
#include <hip/hip_runtime.h>

typedef unsigned short u16;
typedef unsigned int u32;
typedef __attribute__((ext_vector_type(8))) u16 u16x8;
typedef __attribute__((ext_vector_type(8))) __bf16 bf16x8;
typedef __attribute__((ext_vector_type(4))) float f32x4;

__device__ __forceinline__ float b2f(u16 u){ return __uint_as_float(((u32)u)<<16); }
__device__ __forceinline__ u16 f2b(float f){
  u32 b = __float_as_uint(f);
  return (u16)((b + 0x7fffu + ((b>>16)&1u))>>16);
}
__device__ __forceinline__ void gload16(const void* g, void* l){
  __builtin_amdgcn_global_load_lds((__attribute__((address_space(1))) void*)g,
                                   (__attribute__((address_space(3))) void*)l, 16, 0, 0);
}
__device__ __forceinline__ float wred_max(float v){
#pragma unroll
  for (int o=32;o>0;o>>=1) v = fmaxf(v, __shfl_xor(v,o));
  return v;
}
__device__ __forceinline__ float wred_sum(float v){
#pragma unroll
  for (int o=32;o>0;o>>=1) v += __shfl_xor(v,o);
  return v;
}

#define MRR 125480

// ---- fused preprocessing: cast x -> bf16 | weight transposes | agent qkv ----
// grid 6384 x 256: [0,2048) cast, [2048,6144) prep_w, [6144,6384) agent qkv
__global__ void k_pre(const float* __restrict__ x, const float* __restrict__ wvq,
                      const float* __restrict__ wvkv, const float* __restrict__ wout,
                      const float* __restrict__ waqkv,
                      u16* __restrict__ xb, u16* __restrict__ W1T,
                      u16* __restrict__ WoutT, float* __restrict__ aqkv){
  const int bid = blockIdx.x, tid = threadIdx.x;
  if (bid < 2048){
    const int stride = 2048*256;
    for (int i = bid*256 + tid; i < 8030720; i += stride){
      const float4* p = (const float4*)(x + (size_t)i*8);
      float4 a = p[0], b = p[1];
      u16x8 o;
      o[0]=f2b(a.x); o[1]=f2b(a.y); o[2]=f2b(a.z); o[3]=f2b(a.w);
      o[4]=f2b(b.x); o[5]=f2b(b.y); o[6]=f2b(b.z); o[7]=f2b(b.w);
      *(u16x8*)(xb + (size_t)i*8) = o;
    }
  } else if (bid < 6144){
    int id = (bid-2048)*256 + tid;   // [0, 1048576)
    if (id < 786432){
      int n = id >> 9, k = id & 511;
      float v = (n < 512) ? wvq[k*512 + n] : wvkv[k*1024 + (n-512)];
      W1T[id] = f2b(v);
    } else {
      int j = id - 786432;
      int n = j >> 9, k = j & 511;
      WoutT[j] = f2b(wout[k*512 + n]);
    }
  } else {
    int id = (bid-6144)*256 + tid;   // [0, 61440)
    int bt = id / 1536, c = id % 1536;
    const float* xr = x + (size_t)bt*3137*512;
    float s = 0.f;
    for (int k=0;k<512;k++) s += xr[k]*waqkv[k*1536+c];
    aqkv[id] = s;
  }
}

// ---- 256x256 GEMM, 4-slot BK=32 ring, counted vmcnt (round-7 proven, 297us) ----
// A: MxK bf16 row-major, BT: NxK bf16 row-major. C = A * BT^T.
// Fragment-major LDS: every ds_read_b128 is uniform_base + lane*16 (0 conflicts).
// FOUT=0 (GEMM1): routed epilogue -> VQ[row][512] | KH[h][row][64] | VH[h][row][64]
//   (head-major K/V so agent attention reads DENSE 128B rows).
// FOUT=1 (GEMM2): f32 + bias. Plain stores only (nt = 2x write amp, round 4).
template<int FOUT>
__global__ __launch_bounds__(512, 2) void k_gemm256(
    const u16* __restrict__ A, const u16* __restrict__ BT,
    int M, int N, int K, int NX,
    u16* __restrict__ VQ, u16* __restrict__ KH, u16* __restrict__ VH,
    float* __restrict__ Cf, const float* __restrict__ bias)
{
  __shared__ __align__(16) char Ls[4][32768];   // slot: A 16KB | B 16KB
  const int tid = threadIdx.x;
  const int wid = tid >> 6, lane = tid & 63;
  // XCD-bijective swizzle (m204), n-fast work order (FETCH 512->81MB verified)
  const int nwg = gridDim.x, orig = blockIdx.x;
  const int q8 = nwg >> 3, r8 = nwg & 7;
  const int xc = orig & 7, sl = orig >> 3;
  const int work = (xc < r8 ? xc*(q8+1) : r8*(q8+1) + (xc-r8)*q8) + sl;
  const int m0 = (work / NX) * 256, n0 = (work % NX) * 256;
  const size_t K2 = (size_t)K * 2;
  const char* Ab = (const char*)A;
  const char* Bb = (const char*)BT;
  size_t asrc[2], bsrc[2];
  const int ad0 = wid*1024, ad1 = 8192 + wid*1024;  // wave-uniform LDS dest bases
#pragma unroll
  for (int i=0;i<2;i++){
    int row = (i*8 + wid)*16 + (lane & 15);
    int koff = (lane >> 4) << 4;
    int ra = m0 + row; if (ra >= M) ra = M - 1;   // clamp partial last M-tile
    asrc[i] = (size_t)ra * K2 + koff;
    bsrc[i] = (size_t)(n0 + row) * K2 + koff;     // N multiple of 256
  }
#define STAGE(s4, ks) { \
    size_t ko = (size_t)(ks) * 64; \
    gload16(Ab + asrc[0] + ko, Ls[s4] + ad0); \
    gload16(Ab + asrc[1] + ko, Ls[s4] + ad1); \
    gload16(Bb + bsrc[0] + ko, Ls[s4] + 16384 + ad0); \
    gload16(Bb + bsrc[1] + ko, Ls[s4] + 16384 + ad1); }

  f32x4 acc[8][4] = {};
  const int awb = (wid >> 2) * 8192;            // wave's A tiles (8 x 1KB)
  const int bwb = 16384 + (wid & 3) * 4096;     // wave's B tiles (4 x 1KB)
  const int NS = K >> 5;                        // BK=32 slots
  STAGE(0,0) STAGE(1,1) STAGE(2,2)              // 12 loads in flight
  for (int s = 0; s < NS; ++s){
    if (s + 2 < NS)      { asm volatile("s_waitcnt vmcnt(8)" ::: "memory"); }
    else if (s + 1 < NS) { asm volatile("s_waitcnt vmcnt(4)" ::: "memory"); }
    else                 { asm volatile("s_waitcnt vmcnt(0)" ::: "memory"); }
    __builtin_amdgcn_s_barrier();               // slot s in LDS; slot s-1 consumed
    __builtin_amdgcn_sched_barrier(0);
    if (s + 3 < NS) STAGE((s+3)&3, s+3)         // into pos freed at s-1
    const char* base = Ls[s & 3];
    bf16x8 af[8], bfr[4];
#pragma unroll
    for (int i=0;i<4;i++) af[i]  = *(const bf16x8*)(base + awb + i*1024 + lane*16);
#pragma unroll
    for (int i=0;i<4;i++) bfr[i] = *(const bf16x8*)(base + bwb + i*1024 + lane*16);
    asm volatile("s_waitcnt lgkmcnt(0)" ::: "memory");
    __builtin_amdgcn_sched_barrier(0);
    __builtin_amdgcn_s_setprio(1);
#pragma unroll
    for (int mr=0;mr<4;mr++)
#pragma unroll
      for (int nc=0;nc<4;nc++)
        acc[mr][nc] = __builtin_amdgcn_mfma_f32_16x16x32_bf16(af[mr], bfr[nc], acc[mr][nc], 0,0,0);
    __builtin_amdgcn_s_setprio(0);
#pragma unroll
    for (int i=4;i<8;i++) af[i] = *(const bf16x8*)(base + awb + i*1024 + lane*16);
    asm volatile("s_waitcnt lgkmcnt(0)" ::: "memory");
    __builtin_amdgcn_sched_barrier(0);
    __builtin_amdgcn_s_setprio(1);
#pragma unroll
    for (int mr=4;mr<8;mr++)
#pragma unroll
      for (int nc=0;nc<4;nc++)
        acc[mr][nc] = __builtin_amdgcn_mfma_f32_16x16x32_bf16(af[mr], bfr[nc], acc[mr][nc], 0,0,0);
    __builtin_amdgcn_s_setprio(0);
  }
#undef STAGE
  const int wm = (wid >> 2) * 128, wn = (wid & 3) * 64;
  if (FOUT == 0){
    // routed epilogue: col<512 -> VQ row-major; [512,1024) -> KH head-major;
    // [1024,1536) -> VH head-major. Store bases 16-aligned never cross a head.
    const bool full = (m0 + 256 <= M);
#pragma unroll
    for (int mr=0;mr<8;mr++){
#pragma unroll
      for (int nc=0;nc<4;nc++){
#pragma unroll
        for (int rg=0;rg<4;rg++){
          int row = m0 + wm + mr*16 + ((lane>>4)<<2) + rg;
          int col = n0 + wn + nc*16 + (lane&15);
          if (full || row < M){
            u16 ov = f2b(acc[mr][nc][rg]);
            if (col < 512){
              VQ[(size_t)row*512 + col] = ov;
            } else if (col < 1024){
              int h = (col-512)>>6, d = col&63;
              KH[((size_t)h*MRR + row)*64 + d] = ov;
            } else {
              int h = (col-1024)>>6, d = col&63;
              VH[((size_t)h*MRR + row)*64 + d] = ov;
            }
          }
        }
      }
    }
  } else {
    if (m0 + 256 <= M){
#pragma unroll
      for (int mr=0;mr<8;mr++){
#pragma unroll
        for (int nc=0;nc<4;nc++){
#pragma unroll
          for (int rg=0;rg<4;rg++){
            int row = m0 + wm + mr*16 + ((lane>>4)<<2) + rg;
            int col = n0 + wn + nc*16 + (lane&15);
            Cf[(size_t)row*N + col] = acc[mr][nc][rg] + bias[col];
          }
        }
      }
    } else {
#pragma unroll
      for (int mr=0;mr<8;mr++){
#pragma unroll
        for (int nc=0;nc<4;nc++){
#pragma unroll
          for (int rg=0;rg<4;rg++){
            int row = m0 + wm + mr*16 + ((lane>>4)<<2) + rg;
            int col = n0 + wn + nc*16 + (lane&15);
            if (row < M) Cf[(size_t)row*N + col] = acc[mr][nc][rg] + bias[col];
          }
        }
      }
    }
  }
}

// ---------------- agent attention: softmax over 15680 keys, split-K=16 ----------------
// grid 1024 = (bh 64) x (split 16); block 320 = 5 waves (one per query t)
// K/V now head-major: KH[h][row][64] -> staging reads are DENSE 128B rows.
__global__ __launch_bounds__(320) void k_attn_agent(
    const u16* __restrict__ KH, const u16* __restrict__ VH,
    const float* __restrict__ aqkv,
    float* __restrict__ pm, float* __restrict__ pl, float* __restrict__ pacc)
{
  __shared__ __align__(16) char Ksm[16384];   // 128 keys x 64 bf16, XOR-swizzled
  __shared__ __align__(16) char Vsm[16384];
  const int bid = blockIdx.x;
  const int sp = bid & 15, bh = bid >> 4, b = bh >> 3, h = bh & 7;
  const int tid = threadIdx.x, wid = tid >> 6, lane = tid & 63;
  const int q = wid;                           // query t index 0..4
  float qreg[64];
  {
    const float* ap = aqkv + ((size_t)(b*5+q)*1536 + h*64);
#pragma unroll
    for (int d=0; d<64; d++) qreg[d] = ap[d];
  }
  float m = -1e30f, l = 0.f;
  float acc[8] = {0,0,0,0,0,0,0,0};
  const int g0 = sp * 980;                     // 15680/16 keys per split
  const size_t hbase = (size_t)h*MRR;
  for (int c = 0; c < 8; c++){                 // 7*128 + 84 = 980
    for (int idx = tid; idx < 2048; idx += 320){
      int arr = idx >> 10, rem = idx & 1023;
      int r = rem >> 3, seg = rem & 7;
      int loc = c*128 + r; if (loc > 979) loc = 979;
      int gk = g0 + loc;
      int tk = gk / 3136, nv = gk - tk*3136;
      size_t row = (size_t)(b*5+tk)*3137 + 1 + nv;
      const u16* srcp = (arr ? VH : KH) + (hbase + row)*64 + seg*8;
      u16x8 v = *(const u16x8*)srcp;
      char* dst = arr ? Vsm : Ksm;
      *(u16x8*)(dst + r*128 + ((seg*16) ^ ((r&7)<<4))) = v;
    }
    __syncthreads();
    float s0 = 0.f, s1 = 0.f;
#pragma unroll
    for (int seg=0; seg<8; seg++){
      const int r0 = lane, r1 = 64 + lane;
      u16x8 k0 = *(const u16x8*)(Ksm + r0*128 + ((seg*16) ^ ((r0&7)<<4)));
      u16x8 k1 = *(const u16x8*)(Ksm + r1*128 + ((seg*16) ^ ((r1&7)<<4)));
#pragma unroll
      for (int j=0;j<8;j++){
        s0 += qreg[seg*8+j]*b2f(k0[j]);
        s1 += qreg[seg*8+j]*b2f(k1[j]);
      }
    }
    s0 *= 0.125f; s1 *= 0.125f;
    const int locbase = c*128;
    if (locbase + lane >= 980)      s0 = -1e30f;
    if (locbase + 64 + lane >= 980) s1 = -1e30f;
    float cmax = wred_max(fmaxf(s0, s1));
    float mn = fmaxf(m, cmax);
    float resc = __expf(m - mn);
    float p0 = (s0 > -1e29f) ? __expf(s0 - mn) : 0.f;
    float p1 = (s1 > -1e29f) ? __expf(s1 - mn) : 0.f;
    l = l*resc + wred_sum(p0 + p1);
#pragma unroll
    for (int j=0;j<8;j++) acc[j] *= resc;
    const int g = lane >> 3, cc = lane & 7;
#pragma unroll
    for (int i=0;i<16;i++){
      int k = i*8 + g;
      u16x8 vv = *(const u16x8*)(Vsm + k*128 + ((cc*16) ^ ((k&7)<<4)));
      float p = (i < 8) ? __shfl(p0, k) : __shfl(p1, k-64);
#pragma unroll
      for (int j=0;j<8;j++) acc[j] += p*b2f(vv[j]);
    }
    m = mn;
    __syncthreads();
  }
#pragma unroll
  for (int j=0;j<8;j++){
    float v = acc[j];
    v += __shfl_xor(v, 8); v += __shfl_xor(v, 16); v += __shfl_xor(v, 32);
    acc[j] = v;
  }
  const int base = (bh*16 + sp)*5 + q;
  if (lane == 0){ pm[base] = m; pl[base] = l; }
  if (lane < 8){
    float* pa = pacc + (size_t)base*64 + lane*8;
#pragma unroll
    for (int j=0;j<8;j++) pa[j] = acc[j];
  }
}

// ---- frame attention (k=5)+mask -> v rows of IN; fused split-K combine -> a rows ----
// grid 4000 x 256: [0,3920) frame (490 per b), [3920,4000) combine (4 per block)
__global__ __launch_bounds__(256) void k_attn_frame(
    const u16* __restrict__ VQ, const float* __restrict__ aqkv,
    const float* __restrict__ mask, const float* __restrict__ pm,
    const float* __restrict__ pl, const float* __restrict__ pacc,
    u16* __restrict__ IN)
{
  const int bid = blockIdx.x, tid = threadIdx.x;
  if (bid < 3920){
    __shared__ float Ka[5][8][68];
    __shared__ float Va[5][8][68];
    const int b = bid / 490, bx = bid % 490;
    for (int i = tid; i < 2560; i += 256){
      int t = i >> 9, rem = i & 511, hh = rem >> 6, d = rem & 63;
      const float* src = aqkv + (size_t)(b*5+t)*1536;
      Ka[t][hh][d] = src[512 + hh*64 + d];
      Va[t][hh][d] = src[1024 + hh*64 + d];
    }
    __syncthreads();
    const int task = bx*256 + tid;   // 0..125439
    const int h = task & 7, rl = task >> 3;
    const int f = rl / 3136, nv = rl - f*3136;
    const int bt = b*5 + f;
    const size_t r1 = (size_t)bt*3137 + 1 + nv;
    const u16* qp = VQ + r1*512 + h*64;   // vq slice (row-major 512)
    float qf[64];
#pragma unroll
    for (int sg=0; sg<8; sg++){
      u16x8 v = *(const u16x8*)(qp + sg*8);
#pragma unroll
      for (int j=0;j<8;j++) qf[sg*8+j] = b2f(v[j]);
    }
    float sd[5];
#pragma unroll
    for (int t=0;t<5;t++){
      float s = 0.f;
#pragma unroll
      for (int d=0;d<64;d++) s += qf[d]*Ka[t][h][d];
      sd[t] = s*0.125f;
    }
    float mx = sd[0];
#pragma unroll
    for (int t=1;t<5;t++) mx = fmaxf(mx, sd[t]);
    float p[5], ps = 0.f;
#pragma unroll
    for (int t=0;t<5;t++){ p[t] = __expf(sd[t]-mx); ps += p[t]; }
    const float mv = mask[(size_t)bt*3136 + nv] / ps;   // fold mask into normalizer
    u16* op = IN + r1*512 + h*64;
#pragma unroll
    for (int sg=0; sg<8; sg++){
      u16x8 o;
#pragma unroll
      for (int j=0;j<8;j++){
        const int d = sg*8+j;
        float v = 0.f;
#pragma unroll
        for (int t=0;t<5;t++) v += p[t]*Va[t][h][d];
        o[j] = f2b(v*mv);
      }
      *(u16x8*)(op + sg*8) = o;
    }
  } else {
    // combine: 4 (b,h,q) tasks per block, 64 lanes each over d
    const int id = (bid - 3920)*4 + (tid >> 6);   // [0,320)
    const int d = tid & 63;
    const int q = id % 5, t2 = id / 5;
    const int h = t2 & 7, b = t2 >> 3;
    const int bh = b*8 + h;
    float ms = -1e30f;
#pragma unroll
    for (int s2=0;s2<16;s2++) ms = fmaxf(ms, pm[(bh*16+s2)*5+q]);
    float L = 0.f, o = 0.f;
#pragma unroll
    for (int s2=0;s2<16;s2++){
      int base = (bh*16+s2)*5+q;
      float w = __expf(pm[base]-ms);
      L += w*pl[base];
      o += w*pacc[(size_t)base*64 + d];
    }
    IN[(size_t)(b*5+q)*3137*512 + h*64 + d] = f2b(o / L);
  }
}

extern "C" void kernel_launch(void* const* d_in, const int* in_sizes, int n_in,
                              void* d_out, int out_size, void* d_ws, size_t ws_size,
                              hipStream_t stream)
{
  const float* x      = (const float*)d_in[0];
  const float* mask   = (const float*)d_in[1];
  const float* w_vq   = (const float*)d_in[2];
  const float* w_vkv  = (const float*)d_in[3];
  const float* w_aqkv = (const float*)d_in[4];
  const float* w_out  = (const float*)d_in[5];
  const float* b_out  = (const float*)d_in[6];
  float* out = (float*)d_out;
  char* ws = (char*)d_ws;

  constexpr size_t MR = 125480;                          // 40*3137
  constexpr size_t OFF_XB   = 0;                         // M x 512 bf16 (GEMM1 A; later IN)
  constexpr size_t OFF_VQ   = OFF_XB + MR*512*2;         // M x 512 bf16 row-major
  constexpr size_t OFF_KH   = OFF_VQ + MR*512*2;         // 8 x M x 64 bf16 head-major
  constexpr size_t OFF_VH   = OFF_KH + MR*512*2;         // 8 x M x 64 bf16 head-major
  constexpr size_t OFF_W1T  = OFF_VH + MR*512*2;         // 1536x512 bf16
  constexpr size_t OFF_WOT  = OFF_W1T + 1536*512*2;      // 512x512 bf16
  constexpr size_t OFF_AQKV = OFF_WOT + 512*512*2;       // 40x1536 f32
  constexpr size_t OFF_PM   = OFF_AQKV + 40*1536*4;      // 5120 f32
  constexpr size_t OFF_PL   = OFF_PM + 5120*4;           // 5120 f32
  constexpr size_t OFF_PACC = OFF_PL + 5120*4;           // 5120*64 f32

  u16* Xb     = (u16*)(ws + OFF_XB);
  u16* VQ     = (u16*)(ws + OFF_VQ);
  u16* KH     = (u16*)(ws + OFF_KH);
  u16* VH     = (u16*)(ws + OFF_VH);
  u16* W1T    = (u16*)(ws + OFF_W1T);
  u16* WoutT  = (u16*)(ws + OFF_WOT);
  float* aqkv = (float*)(ws + OFF_AQKV);
  float* pm   = (float*)(ws + OFF_PM);
  float* pl   = (float*)(ws + OFF_PL);
  float* pacc = (float*)(ws + OFF_PACC);

  k_pre<<<6384, 256, 0, stream>>>(x, w_vq, w_vkv, w_out, w_aqkv, Xb, W1T, WoutT, aqkv);
  k_gemm256<0><<<2946, 512, 0, stream>>>(Xb, W1T, (int)MR, 1536, 512, 6,
                                         VQ, KH, VH, nullptr, nullptr);
  k_attn_agent<<<1024, 320, 0, stream>>>(KH, VH, aqkv, pm, pl, pacc);
  k_attn_frame<<<4000, 256, 0, stream>>>(VQ, aqkv, mask, pm, pl, pacc, Xb);
  k_gemm256<1><<<982, 512, 0, stream>>>(Xb, WoutT, (int)MR, 512, 512, 2,
                                        nullptr, nullptr, nullptr, out, b_out);
}

// Round 12
// 843.739 us; speedup vs baseline: 1.1000x; 1.0192x over previous
//
#include <hip/hip_runtime.h>

typedef unsigned short u16;
typedef unsigned int u32;
typedef __attribute__((ext_vector_type(8))) u16 u16x8;
typedef __attribute__((ext_vector_type(8))) __bf16 bf16x8;
typedef __attribute__((ext_vector_type(4))) float f32x4;

__device__ __forceinline__ float b2f(u16 u){ return __uint_as_float(((u32)u)<<16); }
__device__ __forceinline__ u16 f2b(float f){
  u32 b = __float_as_uint(f);
  return (u16)((b + 0x7fffu + ((b>>16)&1u))>>16);
}
__device__ __forceinline__ void gload16(const void* g, void* l){
  __builtin_amdgcn_global_load_lds((__attribute__((address_space(1))) void*)g,
                                   (__attribute__((address_space(3))) void*)l, 16, 0, 0);
}
__device__ __forceinline__ float wred_max(float v){
#pragma unroll
  for (int o=32;o>0;o>>=1) v = fmaxf(v, __shfl_xor(v,o));
  return v;
}
__device__ __forceinline__ float wred_sum(float v){
#pragma unroll
  for (int o=32;o>0;o>>=1) v += __shfl_xor(v,o);
  return v;
}

#define MRR 125480

// ---- fused preprocessing: cast x -> bf16 | weight transposes | agent qkv ----
// grid 6384 x 256: [0,2048) cast, [2048,6144) prep_w, [6144,6384) agent qkv
__global__ void k_pre(const float* __restrict__ x, const float* __restrict__ wvq,
                      const float* __restrict__ wvkv, const float* __restrict__ wout,
                      const float* __restrict__ waqkv,
                      u16* __restrict__ xb, u16* __restrict__ W1T,
                      u16* __restrict__ WoutT, float* __restrict__ aqkv){
  const int bid = blockIdx.x, tid = threadIdx.x;
  if (bid < 2048){
    const int stride = 2048*256;
    for (int i = bid*256 + tid; i < 8030720; i += stride){
      const float4* p = (const float4*)(x + (size_t)i*8);
      float4 a = p[0], b = p[1];
      u16x8 o;
      o[0]=f2b(a.x); o[1]=f2b(a.y); o[2]=f2b(a.z); o[3]=f2b(a.w);
      o[4]=f2b(b.x); o[5]=f2b(b.y); o[6]=f2b(b.z); o[7]=f2b(b.w);
      *(u16x8*)(xb + (size_t)i*8) = o;
    }
  } else if (bid < 6144){
    int id = (bid-2048)*256 + tid;   // [0, 1048576)
    if (id < 786432){
      int n = id >> 9, k = id & 511;
      float v = (n < 512) ? wvq[k*512 + n] : wvkv[k*1024 + (n-512)];
      W1T[id] = f2b(v);
    } else {
      int j = id - 786432;
      int n = j >> 9, k = j & 511;
      WoutT[j] = f2b(wout[k*512 + n]);
    }
  } else {
    int id = (bid-6144)*256 + tid;   // [0, 61440)
    int bt = id / 1536, c = id % 1536;
    const float* xr = x + (size_t)bt*3137*512;
    float s = 0.f;
    for (int k=0;k<512;k++) s += xr[k]*waqkv[k*1536+c];
    aqkv[id] = s;
  }
}

// ---- 256x256 GEMM, 4-slot BK=32 ring, counted vmcnt (round-7 proven, 297us) ----
// A: MxK bf16 row-major, BT: NxK bf16 row-major. C = A * BT^T.
// Fragment-major LDS: every ds_read_b128 is uniform_base + lane*16 (0 conflicts).
// FOUT=0 (GEMM1): routed epilogue -> VQ[row][512] | KH[h][row][64] | VH[h][row][64].
//   Routing branch hoisted to (mr,nc) on WAVE-UNIFORM colb (r11's per-lane
//   branch cost +78us -- exec-mask churn around every scalar store).
// FOUT=1 (GEMM2): f32 + bias. Plain stores only (nt = 2x write amp, round 4).
template<int FOUT>
__global__ __launch_bounds__(512, 2) void k_gemm256(
    const u16* __restrict__ A, const u16* __restrict__ BT,
    int M, int N, int K, int NX,
    u16* __restrict__ VQ, u16* __restrict__ KH, u16* __restrict__ VH,
    float* __restrict__ Cf, const float* __restrict__ bias)
{
  __shared__ __align__(16) char Ls[4][32768];   // slot: A 16KB | B 16KB
  const int tid = threadIdx.x;
  const int wid = tid >> 6, lane = tid & 63;
  // XCD-bijective swizzle (m204), n-fast work order (FETCH 512->81MB verified)
  const int nwg = gridDim.x, orig = blockIdx.x;
  const int q8 = nwg >> 3, r8 = nwg & 7;
  const int xc = orig & 7, sl = orig >> 3;
  const int work = (xc < r8 ? xc*(q8+1) : r8*(q8+1) + (xc-r8)*q8) + sl;
  const int m0 = (work / NX) * 256, n0 = (work % NX) * 256;
  const size_t K2 = (size_t)K * 2;
  const char* Ab = (const char*)A;
  const char* Bb = (const char*)BT;
  size_t asrc[2], bsrc[2];
  const int ad0 = wid*1024, ad1 = 8192 + wid*1024;  // wave-uniform LDS dest bases
#pragma unroll
  for (int i=0;i<2;i++){
    int row = (i*8 + wid)*16 + (lane & 15);
    int koff = (lane >> 4) << 4;
    int ra = m0 + row; if (ra >= M) ra = M - 1;   // clamp partial last M-tile
    asrc[i] = (size_t)ra * K2 + koff;
    bsrc[i] = (size_t)(n0 + row) * K2 + koff;     // N multiple of 256
  }
#define STAGE(s4, ks) { \
    size_t ko = (size_t)(ks) * 64; \
    gload16(Ab + asrc[0] + ko, Ls[s4] + ad0); \
    gload16(Ab + asrc[1] + ko, Ls[s4] + ad1); \
    gload16(Bb + bsrc[0] + ko, Ls[s4] + 16384 + ad0); \
    gload16(Bb + bsrc[1] + ko, Ls[s4] + 16384 + ad1); }

  f32x4 acc[8][4] = {};
  const int awb = (wid >> 2) * 8192;            // wave's A tiles (8 x 1KB)
  const int bwb = 16384 + (wid & 3) * 4096;     // wave's B tiles (4 x 1KB)
  const int NS = K >> 5;                        // BK=32 slots
  STAGE(0,0) STAGE(1,1) STAGE(2,2)              // 12 loads in flight
  for (int s = 0; s < NS; ++s){
    if (s + 2 < NS)      { asm volatile("s_waitcnt vmcnt(8)" ::: "memory"); }
    else if (s + 1 < NS) { asm volatile("s_waitcnt vmcnt(4)" ::: "memory"); }
    else                 { asm volatile("s_waitcnt vmcnt(0)" ::: "memory"); }
    __builtin_amdgcn_s_barrier();               // slot s in LDS; slot s-1 consumed
    __builtin_amdgcn_sched_barrier(0);
    if (s + 3 < NS) STAGE((s+3)&3, s+3)         // into pos freed at s-1
    const char* base = Ls[s & 3];
    bf16x8 af[8], bfr[4];
#pragma unroll
    for (int i=0;i<4;i++) af[i]  = *(const bf16x8*)(base + awb + i*1024 + lane*16);
#pragma unroll
    for (int i=0;i<4;i++) bfr[i] = *(const bf16x8*)(base + bwb + i*1024 + lane*16);
    asm volatile("s_waitcnt lgkmcnt(0)" ::: "memory");
    __builtin_amdgcn_sched_barrier(0);
    __builtin_amdgcn_s_setprio(1);
#pragma unroll
    for (int mr=0;mr<4;mr++)
#pragma unroll
      for (int nc=0;nc<4;nc++)
        acc[mr][nc] = __builtin_amdgcn_mfma_f32_16x16x32_bf16(af[mr], bfr[nc], acc[mr][nc], 0,0,0);
    __builtin_amdgcn_s_setprio(0);
#pragma unroll
    for (int i=4;i<8;i++) af[i] = *(const bf16x8*)(base + awb + i*1024 + lane*16);
    asm volatile("s_waitcnt lgkmcnt(0)" ::: "memory");
    __builtin_amdgcn_sched_barrier(0);
    __builtin_amdgcn_s_setprio(1);
#pragma unroll
    for (int mr=4;mr<8;mr++)
#pragma unroll
      for (int nc=0;nc<4;nc++)
        acc[mr][nc] = __builtin_amdgcn_mfma_f32_16x16x32_bf16(af[mr], bfr[nc], acc[mr][nc], 0,0,0);
    __builtin_amdgcn_s_setprio(0);
  }
#undef STAGE
  const int wm = (wid >> 2) * 128, wn = (wid & 3) * 64;
  if (FOUT == 0){
    // routed epilogue, WAVE-UNIFORM branch per (nc): colb = n0+wn+nc*16 is
    // 16-aligned and never crosses a 64-col head boundary for the 16-lane group.
    const bool full = (m0 + 256 <= M);
    const int ln = lane & 15, lq4 = (lane >> 4) << 2;
#pragma unroll
    for (int nc=0;nc<4;nc++){
      const int colb = n0 + wn + nc*16;
      u16* bp; size_t ld;
      if (colb < 512){
        bp = VQ + colb; ld = 512;
      } else if (colb < 1024){
        const int cb = colb - 512;
        bp = KH + (size_t)(cb >> 6)*MRR*64 + (cb & 63); ld = 64;
      } else {
        const int cb = colb - 1024;
        bp = VH + (size_t)(cb >> 6)*MRR*64 + (cb & 63); ld = 64;
      }
#pragma unroll
      for (int mr=0;mr<8;mr++){
#pragma unroll
        for (int rg=0;rg<4;rg++){
          const int row = m0 + wm + mr*16 + lq4 + rg;
          if (full || row < M)
            bp[(size_t)row*ld + ln] = f2b(acc[mr][nc][rg]);
        }
      }
    }
  } else {
    if (m0 + 256 <= M){
#pragma unroll
      for (int mr=0;mr<8;mr++){
#pragma unroll
        for (int nc=0;nc<4;nc++){
#pragma unroll
          for (int rg=0;rg<4;rg++){
            int row = m0 + wm + mr*16 + ((lane>>4)<<2) + rg;
            int col = n0 + wn + nc*16 + (lane&15);
            Cf[(size_t)row*N + col] = acc[mr][nc][rg] + bias[col];
          }
        }
      }
    } else {
#pragma unroll
      for (int mr=0;mr<8;mr++){
#pragma unroll
        for (int nc=0;nc<4;nc++){
#pragma unroll
          for (int rg=0;rg<4;rg++){
            int row = m0 + wm + mr*16 + ((lane>>4)<<2) + rg;
            int col = n0 + wn + nc*16 + (lane&15);
            if (row < M) Cf[(size_t)row*N + col] = acc[mr][nc][rg] + bias[col];
          }
        }
      }
    }
  }
}

// ---------------- agent attention: softmax over 15680 keys, split-K=16 ----------------
// grid 1024 = (bh 64) x (split 16); block 320 = 5 waves (one per query t)
// K/V head-major: KH[h][row][64] -> staging reads are DENSE 128B rows.
__global__ __launch_bounds__(320) void k_attn_agent(
    const u16* __restrict__ KH, const u16* __restrict__ VH,
    const float* __restrict__ aqkv,
    float* __restrict__ pm, float* __restrict__ pl, float* __restrict__ pacc)
{
  __shared__ __align__(16) char Ksm[16384];   // 128 keys x 64 bf16, XOR-swizzled
  __shared__ __align__(16) char Vsm[16384];
  const int bid = blockIdx.x;
  const int sp = bid & 15, bh = bid >> 4, b = bh >> 3, h = bh & 7;
  const int tid = threadIdx.x, wid = tid >> 6, lane = tid & 63;
  const int q = wid;                           // query t index 0..4
  float qreg[64];
  {
    const float* ap = aqkv + ((size_t)(b*5+q)*1536 + h*64);
#pragma unroll
    for (int d=0; d<64; d++) qreg[d] = ap[d];
  }
  float m = -1e30f, l = 0.f;
  float acc[8] = {0,0,0,0,0,0,0,0};
  const int g0 = sp * 980;                     // 15680/16 keys per split
  const size_t hbase = (size_t)h*MRR;
  for (int c = 0; c < 8; c++){                 // 7*128 + 84 = 980
    for (int idx = tid; idx < 2048; idx += 320){
      int arr = idx >> 10, rem = idx & 1023;
      int r = rem >> 3, seg = rem & 7;
      int loc = c*128 + r; if (loc > 979) loc = 979;
      int gk = g0 + loc;
      int tk = gk / 3136, nv = gk - tk*3136;
      size_t row = (size_t)(b*5+tk)*3137 + 1 + nv;
      const u16* srcp = (arr ? VH : KH) + (hbase + row)*64 + seg*8;
      u16x8 v = *(const u16x8*)srcp;
      char* dst = arr ? Vsm : Ksm;
      *(u16x8*)(dst + r*128 + ((seg*16) ^ ((r&7)<<4))) = v;
    }
    __syncthreads();
    float s0 = 0.f, s1 = 0.f;
#pragma unroll
    for (int seg=0; seg<8; seg++){
      const int r0 = lane, r1 = 64 + lane;
      u16x8 k0 = *(const u16x8*)(Ksm + r0*128 + ((seg*16) ^ ((r0&7)<<4)));
      u16x8 k1 = *(const u16x8*)(Ksm + r1*128 + ((seg*16) ^ ((r1&7)<<4)));
#pragma unroll
      for (int j=0;j<8;j++){
        s0 += qreg[seg*8+j]*b2f(k0[j]);
        s1 += qreg[seg*8+j]*b2f(k1[j]);
      }
    }
    s0 *= 0.125f; s1 *= 0.125f;
    const int locbase = c*128;
    if (locbase + lane >= 980)      s0 = -1e30f;
    if (locbase + 64 + lane >= 980) s1 = -1e30f;
    float cmax = wred_max(fmaxf(s0, s1));
    float mn = fmaxf(m, cmax);
    float resc = __expf(m - mn);
    float p0 = (s0 > -1e29f) ? __expf(s0 - mn) : 0.f;
    float p1 = (s1 > -1e29f) ? __expf(s1 - mn) : 0.f;
    l = l*resc + wred_sum(p0 + p1);
#pragma unroll
    for (int j=0;j<8;j++) acc[j] *= resc;
    const int g = lane >> 3, cc = lane & 7;
#pragma unroll
    for (int i=0;i<16;i++){
      int k = i*8 + g;
      u16x8 vv = *(const u16x8*)(Vsm + k*128 + ((cc*16) ^ ((k&7)<<4)));
      float p = (i < 8) ? __shfl(p0, k) : __shfl(p1, k-64);
#pragma unroll
      for (int j=0;j<8;j++) acc[j] += p*b2f(vv[j]);
    }
    m = mn;
    __syncthreads();
  }
#pragma unroll
  for (int j=0;j<8;j++){
    float v = acc[j];
    v += __shfl_xor(v, 8); v += __shfl_xor(v, 16); v += __shfl_xor(v, 32);
    acc[j] = v;
  }
  const int base = (bh*16 + sp)*5 + q;
  if (lane == 0){ pm[base] = m; pl[base] = l; }
  if (lane < 8){
    float* pa = pacc + (size_t)base*64 + lane*8;
#pragma unroll
    for (int j=0;j<8;j++) pa[j] = acc[j];
  }
}

// ---- frame attention (k=5)+mask -> v rows of IN; fused split-K combine -> a rows ----
// grid 4000 x 256: [0,3920) frame (490 per b), [3920,4000) combine (4 per block)
__global__ __launch_bounds__(256) void k_attn_frame(
    const u16* __restrict__ VQ, const float* __restrict__ aqkv,
    const float* __restrict__ mask, const float* __restrict__ pm,
    const float* __restrict__ pl, const float* __restrict__ pacc,
    u16* __restrict__ IN)
{
  const int bid = blockIdx.x, tid = threadIdx.x;
  if (bid < 3920){
    __shared__ float Ka[5][8][68];
    __shared__ float Va[5][8][68];
    const int b = bid / 490, bx = bid % 490;
    for (int i = tid; i < 2560; i += 256){
      int t = i >> 9, rem = i & 511, hh = rem >> 6, d = rem & 63;
      const float* src = aqkv + (size_t)(b*5+t)*1536;
      Ka[t][hh][d] = src[512 + hh*64 + d];
      Va[t][hh][d] = src[1024 + hh*64 + d];
    }
    __syncthreads();
    const int task = bx*256 + tid;   // 0..125439
    const int h = task & 7, rl = task >> 3;
    const int f = rl / 3136, nv = rl - f*3136;
    const int bt = b*5 + f;
    const size_t r1 = (size_t)bt*3137 + 1 + nv;
    const u16* qp = VQ + r1*512 + h*64;   // vq slice (row-major 512)
    float qf[64];
#pragma unroll
    for (int sg=0; sg<8; sg++){
      u16x8 v = *(const u16x8*)(qp + sg*8);
#pragma unroll
      for (int j=0;j<8;j++) qf[sg*8+j] = b2f(v[j]);
    }
    float sd[5];
#pragma unroll
    for (int t=0;t<5;t++){
      float s = 0.f;
#pragma unroll
      for (int d=0;d<64;d++) s += qf[d]*Ka[t][h][d];
      sd[t] = s*0.125f;
    }
    float mx = sd[0];
#pragma unroll
    for (int t=1;t<5;t++) mx = fmaxf(mx, sd[t]);
    float p[5], ps = 0.f;
#pragma unroll
    for (int t=0;t<5;t++){ p[t] = __expf(sd[t]-mx); ps += p[t]; }
    const float mv = mask[(size_t)bt*3136 + nv] / ps;   // fold mask into normalizer
    u16* op = IN + r1*512 + h*64;
#pragma unroll
    for (int sg=0; sg<8; sg++){
      u16x8 o;
#pragma unroll
      for (int j=0;j<8;j++){
        const int d = sg*8+j;
        float v = 0.f;
#pragma unroll
        for (int t=0;t<5;t++) v += p[t]*Va[t][h][d];
        o[j] = f2b(v*mv);
      }
      *(u16x8*)(op + sg*8) = o;
    }
  } else {
    // combine: 4 (b,h,q) tasks per block, 64 lanes each over d
    const int id = (bid - 3920)*4 + (tid >> 6);   // [0,320)
    const int d = tid & 63;
    const int q = id % 5, t2 = id / 5;
    const int h = t2 & 7, b = t2 >> 3;
    const int bh = b*8 + h;
    float ms = -1e30f;
#pragma unroll
    for (int s2=0;s2<16;s2++) ms = fmaxf(ms, pm[(bh*16+s2)*5+q]);
    float L = 0.f, o = 0.f;
#pragma unroll
    for (int s2=0;s2<16;s2++){
      int base = (bh*16+s2)*5+q;
      float w = __expf(pm[base]-ms);
      L += w*pl[base];
      o += w*pacc[(size_t)base*64 + d];
    }
    IN[(size_t)(b*5+q)*3137*512 + h*64 + d] = f2b(o / L);
  }
}

extern "C" void kernel_launch(void* const* d_in, const int* in_sizes, int n_in,
                              void* d_out, int out_size, void* d_ws, size_t ws_size,
                              hipStream_t stream)
{
  const float* x      = (const float*)d_in[0];
  const float* mask   = (const float*)d_in[1];
  const float* w_vq   = (const float*)d_in[2];
  const float* w_vkv  = (const float*)d_in[3];
  const float* w_aqkv = (const float*)d_in[4];
  const float* w_out  = (const float*)d_in[5];
  const float* b_out  = (const float*)d_in[6];
  float* out = (float*)d_out;
  char* ws = (char*)d_ws;

  constexpr size_t MR = 125480;                          // 40*3137
  constexpr size_t OFF_XB   = 0;                         // M x 512 bf16 (GEMM1 A; later IN)
  constexpr size_t OFF_VQ   = OFF_XB + MR*512*2;         // M x 512 bf16 row-major
  constexpr size_t OFF_KH   = OFF_VQ + MR*512*2;         // 8 x M x 64 bf16 head-major
  constexpr size_t OFF_VH   = OFF_KH + MR*512*2;         // 8 x M x 64 bf16 head-major
  constexpr size_t OFF_W1T  = OFF_VH + MR*512*2;         // 1536x512 bf16
  constexpr size_t OFF_WOT  = OFF_W1T + 1536*512*2;      // 512x512 bf16
  constexpr size_t OFF_AQKV = OFF_WOT + 512*512*2;       // 40x1536 f32
  constexpr size_t OFF_PM   = OFF_AQKV + 40*1536*4;      // 5120 f32
  constexpr size_t OFF_PL   = OFF_PM + 5120*4;           // 5120 f32
  constexpr size_t OFF_PACC = OFF_PL + 5120*4;           // 5120*64 f32

  u16* Xb     = (u16*)(ws + OFF_XB);
  u16* VQ     = (u16*)(ws + OFF_VQ);
  u16* KH     = (u16*)(ws + OFF_KH);
  u16* VH     = (u16*)(ws + OFF_VH);
  u16* W1T    = (u16*)(ws + OFF_W1T);
  u16* WoutT  = (u16*)(ws + OFF_WOT);
  float* aqkv = (float*)(ws + OFF_AQKV);
  float* pm   = (float*)(ws + OFF_PM);
  float* pl   = (float*)(ws + OFF_PL);
  float* pacc = (float*)(ws + OFF_PACC);

  k_pre<<<6384, 256, 0, stream>>>(x, w_vq, w_vkv, w_out, w_aqkv, Xb, W1T, WoutT, aqkv);
  k_gemm256<0><<<2946, 512, 0, stream>>>(Xb, W1T, (int)MR, 1536, 512, 6,
                                         VQ, KH, VH, nullptr, nullptr);
  k_attn_agent<<<1024, 320, 0, stream>>>(KH, VH, aqkv, pm, pl, pacc);
  k_attn_frame<<<4000, 256, 0, stream>>>(VQ, aqkv, mask, pm, pl, pacc, Xb);
  k_gemm256<1><<<982, 512, 0, stream>>>(Xb, WoutT, (int)MR, 512, 512, 2,
                                        nullptr, nullptr, nullptr, out, b_out);
}

// Round 13
// 784.334 us; speedup vs baseline: 1.1833x; 1.0757x over previous
//
#include <hip/hip_runtime.h>

typedef unsigned short u16;
typedef unsigned int u32;
typedef __attribute__((ext_vector_type(8))) u16 u16x8;
typedef __attribute__((ext_vector_type(8))) __bf16 bf16x8;
typedef __attribute__((ext_vector_type(4))) float f32x4;

__device__ __forceinline__ float b2f(u16 u){ return __uint_as_float(((u32)u)<<16); }
__device__ __forceinline__ u16 f2b(float f){
  u32 b = __float_as_uint(f);
  return (u16)((b + 0x7fffu + ((b>>16)&1u))>>16);
}
__device__ __forceinline__ void gload16(const void* g, void* l){
  __builtin_amdgcn_global_load_lds((__attribute__((address_space(1))) void*)g,
                                   (__attribute__((address_space(3))) void*)l, 16, 0, 0);
}
__device__ __forceinline__ float wred_max(float v){
#pragma unroll
  for (int o=32;o>0;o>>=1) v = fmaxf(v, __shfl_xor(v,o));
  return v;
}
__device__ __forceinline__ float wred_sum(float v){
#pragma unroll
  for (int o=32;o>0;o>>=1) v += __shfl_xor(v,o);
  return v;
}

// out1 column order (set by W1T permutation in k_pre):
//   [0,512)   : vq (original order)
//   512+h*128 : head h's vk(64) | vv(64)  -- K+V contiguous 256B per key row
// so attn_agent reads one dense 256B chunk per (key,head).

// ---- fused preprocessing: cast x -> bf16 | weight transposes | agent qkv ----
// grid 6384 x 256: [0,2048) cast, [2048,6144) prep_w, [6144,6384) agent qkv
__global__ void k_pre(const float* __restrict__ x, const float* __restrict__ wvq,
                      const float* __restrict__ wvkv, const float* __restrict__ wout,
                      const float* __restrict__ waqkv,
                      u16* __restrict__ xb, u16* __restrict__ W1T,
                      u16* __restrict__ WoutT, float* __restrict__ aqkv){
  const int bid = blockIdx.x, tid = threadIdx.x;
  if (bid < 2048){
    const int stride = 2048*256;
    for (int i = bid*256 + tid; i < 8030720; i += stride){
      const float4* p = (const float4*)(x + (size_t)i*8);
      float4 a = p[0], b = p[1];
      u16x8 o;
      o[0]=f2b(a.x); o[1]=f2b(a.y); o[2]=f2b(a.z); o[3]=f2b(a.w);
      o[4]=f2b(b.x); o[5]=f2b(b.y); o[6]=f2b(b.z); o[7]=f2b(b.w);
      *(u16x8*)(xb + (size_t)i*8) = o;
    }
  } else if (bid < 6144){
    int id = (bid-2048)*256 + tid;   // [0, 1048576)
    if (id < 786432){
      int n = id >> 9, k = id & 511;
      float v;
      if (n < 512){
        v = wvq[k*512 + n];
      } else {
        int j = n - 512, h = j >> 7, r = j & 127;
        int c2 = (r < 64) ? (h*64 + r) : (512 + h*64 + (r - 64));   // vk | vv
        v = wvkv[k*1024 + c2];
      }
      W1T[id] = f2b(v);
    } else {
      int j = id - 786432;
      int n = j >> 9, k = j & 511;
      WoutT[j] = f2b(wout[k*512 + n]);
    }
  } else {
    int id = (bid-6144)*256 + tid;   // [0, 61440)
    int bt = id / 1536, c = id % 1536;
    const float* xr = x + (size_t)bt*3137*512;
    float s = 0.f;
    for (int k=0;k<512;k++) s += xr[k]*waqkv[k*1536+c];
    aqkv[id] = s;
  }
}

// ---- 256x256 GEMM, 4-slot BK=32 ring, counted vmcnt (r7-proven, 297us) ----
// A: MxK bf16 row-major, BT: NxK bf16 row-major. C = A * BT^T.
// Fragment-major LDS: every ds_read_b128 is uniform_base + lane*16 (0 conflicts).
// Single-buffer plain epilogue (WRITE=376MB ideal, verified r5-r8). Routed /
// head-major epilogues measured +60us and/or 1.6x write amp (r11/r12) -- and
// nt-stores 2x write amp (r4). DO NOT reintroduce either.
template<int FOUT>
__global__ __launch_bounds__(512, 2) void k_gemm256(
    const u16* __restrict__ A, const u16* __restrict__ BT,
    int M, int N, int K, int NX,
    u16* __restrict__ Cb, float* __restrict__ Cf, const float* __restrict__ bias)
{
  __shared__ __align__(16) char Ls[4][32768];   // slot: A 16KB | B 16KB
  const int tid = threadIdx.x;
  const int wid = tid >> 6, lane = tid & 63;
  // XCD-bijective swizzle (m204), n-fast work order (FETCH 512->81MB verified)
  const int nwg = gridDim.x, orig = blockIdx.x;
  const int q8 = nwg >> 3, r8 = nwg & 7;
  const int xc = orig & 7, sl = orig >> 3;
  const int work = (xc < r8 ? xc*(q8+1) : r8*(q8+1) + (xc-r8)*q8) + sl;
  const int m0 = (work / NX) * 256, n0 = (work % NX) * 256;
  const size_t K2 = (size_t)K * 2;
  const char* Ab = (const char*)A;
  const char* Bb = (const char*)BT;
  size_t asrc[2], bsrc[2];
  const int ad0 = wid*1024, ad1 = 8192 + wid*1024;  // wave-uniform LDS dest bases
#pragma unroll
  for (int i=0;i<2;i++){
    int row = (i*8 + wid)*16 + (lane & 15);
    int koff = (lane >> 4) << 4;
    int ra = m0 + row; if (ra >= M) ra = M - 1;   // clamp partial last M-tile
    asrc[i] = (size_t)ra * K2 + koff;
    bsrc[i] = (size_t)(n0 + row) * K2 + koff;     // N multiple of 256
  }
#define STAGE(s4, ks) { \
    size_t ko = (size_t)(ks) * 64; \
    gload16(Ab + asrc[0] + ko, Ls[s4] + ad0); \
    gload16(Ab + asrc[1] + ko, Ls[s4] + ad1); \
    gload16(Bb + bsrc[0] + ko, Ls[s4] + 16384 + ad0); \
    gload16(Bb + bsrc[1] + ko, Ls[s4] + 16384 + ad1); }

  f32x4 acc[8][4] = {};
  const int awb = (wid >> 2) * 8192;            // wave's A tiles (8 x 1KB)
  const int bwb = 16384 + (wid & 3) * 4096;     // wave's B tiles (4 x 1KB)
  const int NS = K >> 5;                        // BK=32 slots
  STAGE(0,0) STAGE(1,1) STAGE(2,2)              // 12 loads in flight
  for (int s = 0; s < NS; ++s){
    if (s + 2 < NS)      { asm volatile("s_waitcnt vmcnt(8)" ::: "memory"); }
    else if (s + 1 < NS) { asm volatile("s_waitcnt vmcnt(4)" ::: "memory"); }
    else                 { asm volatile("s_waitcnt vmcnt(0)" ::: "memory"); }
    __builtin_amdgcn_s_barrier();               // slot s in LDS; slot s-1 consumed
    __builtin_amdgcn_sched_barrier(0);
    if (s + 3 < NS) STAGE((s+3)&3, s+3)         // into pos freed at s-1
    const char* base = Ls[s & 3];
    bf16x8 af[8], bfr[4];
#pragma unroll
    for (int i=0;i<4;i++) af[i]  = *(const bf16x8*)(base + awb + i*1024 + lane*16);
#pragma unroll
    for (int i=0;i<4;i++) bfr[i] = *(const bf16x8*)(base + bwb + i*1024 + lane*16);
    asm volatile("s_waitcnt lgkmcnt(0)" ::: "memory");
    __builtin_amdgcn_sched_barrier(0);
    __builtin_amdgcn_s_setprio(1);
#pragma unroll
    for (int mr=0;mr<4;mr++)
#pragma unroll
      for (int nc=0;nc<4;nc++)
        acc[mr][nc] = __builtin_amdgcn_mfma_f32_16x16x32_bf16(af[mr], bfr[nc], acc[mr][nc], 0,0,0);
    __builtin_amdgcn_s_setprio(0);
#pragma unroll
    for (int i=4;i<8;i++) af[i] = *(const bf16x8*)(base + awb + i*1024 + lane*16);
    asm volatile("s_waitcnt lgkmcnt(0)" ::: "memory");
    __builtin_amdgcn_sched_barrier(0);
    __builtin_amdgcn_s_setprio(1);
#pragma unroll
    for (int mr=4;mr<8;mr++)
#pragma unroll
      for (int nc=0;nc<4;nc++)
        acc[mr][nc] = __builtin_amdgcn_mfma_f32_16x16x32_bf16(af[mr], bfr[nc], acc[mr][nc], 0,0,0);
    __builtin_amdgcn_s_setprio(0);
  }
#undef STAGE
  const int wm = (wid >> 2) * 128, wn = (wid & 3) * 64;
  if (m0 + 256 <= M){
#pragma unroll
    for (int mr=0;mr<8;mr++){
#pragma unroll
      for (int nc=0;nc<4;nc++){
#pragma unroll
        for (int rg=0;rg<4;rg++){
          int row = m0 + wm + mr*16 + ((lane>>4)<<2) + rg;
          int col = n0 + wn + nc*16 + (lane&15);
          float v = acc[mr][nc][rg];
          if (FOUT) Cf[(size_t)row*N + col] = v + bias[col];
          else      Cb[(size_t)row*N + col] = f2b(v);
        }
      }
    }
  } else {
#pragma unroll
    for (int mr=0;mr<8;mr++){
#pragma unroll
      for (int nc=0;nc<4;nc++){
#pragma unroll
        for (int rg=0;rg<4;rg++){
          int row = m0 + wm + mr*16 + ((lane>>4)<<2) + rg;
          int col = n0 + wn + nc*16 + (lane&15);
          if (row < M){
            float v = acc[mr][nc][rg];
            if (FOUT) Cf[(size_t)row*N + col] = v + bias[col];
            else      Cb[(size_t)row*N + col] = f2b(v);
          }
        }
      }
    }
  }
}

// ---------------- agent attention: softmax over 15680 keys, split-K=16 ----------------
// grid 1024 = (bh 64) x (split 16); block 320 = 5 waves (one per query t)
// out1 per-head K/V chunks: cols 512+h*128 = [vk64|vv64] -> staging reads one
// DENSE 256B chunk per key (16 consecutive lanes), 4 full lines, no waste.
__global__ __launch_bounds__(320) void k_attn_agent(
    const u16* __restrict__ out1, const float* __restrict__ aqkv,
    float* __restrict__ pm, float* __restrict__ pl, float* __restrict__ pacc)
{
  __shared__ __align__(16) char Ksm[16384];   // 128 keys x 64 bf16, XOR-swizzled
  __shared__ __align__(16) char Vsm[16384];
  const int bid = blockIdx.x;
  const int sp = bid & 15, bh = bid >> 4, b = bh >> 3, h = bh & 7;
  const int tid = threadIdx.x, wid = tid >> 6, lane = tid & 63;
  const int q = wid;                           // query t index 0..4
  float qreg[64];
  {
    const float* ap = aqkv + ((size_t)(b*5+q)*1536 + h*64);
#pragma unroll
    for (int d=0; d<64; d++) qreg[d] = ap[d];
  }
  float m = -1e30f, l = 0.f;
  float acc[8] = {0,0,0,0,0,0,0,0};
  const int g0 = sp * 980;                     // 15680/16 keys per split
  for (int c = 0; c < 8; c++){                 // 7*128 + 84 = 980
    for (int idx = tid; idx < 2048; idx += 320){
      int r = idx >> 4, g = idx & 15;          // 16 granules = K(8)|V(8) per key
      int loc = c*128 + r; if (loc > 979) loc = 979;
      int gk = g0 + loc;
      int tk = gk / 3136, nv = gk - tk*3136;
      size_t grow = (size_t)((b*5+tk)*3137 + 1 + nv)*1536 + 512 + h*128 + g*8;
      u16x8 v = *(const u16x8*)(out1 + grow);
      char* dst = (g < 8) ? Ksm : Vsm;
      int seg = g & 7;
      *(u16x8*)(dst + r*128 + ((seg*16) ^ ((r&7)<<4))) = v;
    }
    __syncthreads();
    float s0 = 0.f, s1 = 0.f;
#pragma unroll
    for (int seg=0; seg<8; seg++){
      const int r0 = lane, r1 = 64 + lane;
      u16x8 k0 = *(const u16x8*)(Ksm + r0*128 + ((seg*16) ^ ((r0&7)<<4)));
      u16x8 k1 = *(const u16x8*)(Ksm + r1*128 + ((seg*16) ^ ((r1&7)<<4)));
#pragma unroll
      for (int j=0;j<8;j++){
        s0 += qreg[seg*8+j]*b2f(k0[j]);
        s1 += qreg[seg*8+j]*b2f(k1[j]);
      }
    }
    s0 *= 0.125f; s1 *= 0.125f;
    const int locbase = c*128;
    if (locbase + lane >= 980)      s0 = -1e30f;
    if (locbase + 64 + lane >= 980) s1 = -1e30f;
    float cmax = wred_max(fmaxf(s0, s1));
    float mn = fmaxf(m, cmax);
    float resc = __expf(m - mn);
    float p0 = (s0 > -1e29f) ? __expf(s0 - mn) : 0.f;
    float p1 = (s1 > -1e29f) ? __expf(s1 - mn) : 0.f;
    l = l*resc + wred_sum(p0 + p1);
#pragma unroll
    for (int j=0;j<8;j++) acc[j] *= resc;
    const int g = lane >> 3, cc = lane & 7;
#pragma unroll
    for (int i=0;i<16;i++){
      int k = i*8 + g;
      u16x8 vv = *(const u16x8*)(Vsm + k*128 + ((cc*16) ^ ((k&7)<<4)));
      float p = (i < 8) ? __shfl(p0, k) : __shfl(p1, k-64);
#pragma unroll
      for (int j=0;j<8;j++) acc[j] += p*b2f(vv[j]);
    }
    m = mn;
    __syncthreads();
  }
#pragma unroll
  for (int j=0;j<8;j++){
    float v = acc[j];
    v += __shfl_xor(v, 8); v += __shfl_xor(v, 16); v += __shfl_xor(v, 32);
    acc[j] = v;
  }
  const int base = (bh*16 + sp)*5 + q;
  if (lane == 0){ pm[base] = m; pl[base] = l; }
  if (lane < 8){
    float* pa = pacc + (size_t)base*64 + lane*8;
#pragma unroll
    for (int j=0;j<8;j++) pa[j] = acc[j];
  }
}

// ---- frame attention (k=5)+mask -> v rows of IN; fused split-K combine -> a rows ----
// grid 4000 x 256: [0,3920) frame (490 per b), [3920,4000) combine (4 per block)
__global__ __launch_bounds__(256) void k_attn_frame(
    const u16* __restrict__ out1, const float* __restrict__ aqkv,
    const float* __restrict__ mask, const float* __restrict__ pm,
    const float* __restrict__ pl, const float* __restrict__ pacc,
    u16* __restrict__ IN)
{
  const int bid = blockIdx.x, tid = threadIdx.x;
  if (bid < 3920){
    __shared__ float Ka[5][8][68];
    __shared__ float Va[5][8][68];
    const int b = bid / 490, bx = bid % 490;
    for (int i = tid; i < 2560; i += 256){
      int t = i >> 9, rem = i & 511, hh = rem >> 6, d = rem & 63;
      const float* src = aqkv + (size_t)(b*5+t)*1536;
      Ka[t][hh][d] = src[512 + hh*64 + d];
      Va[t][hh][d] = src[1024 + hh*64 + d];
    }
    __syncthreads();
    const int task = bx*256 + tid;   // 0..125439
    const int h = task & 7, rl = task >> 3;
    const int f = rl / 3136, nv = rl - f*3136;
    const int bt = b*5 + f;
    const size_t r1 = (size_t)bt*3137 + 1 + nv;
    const u16* qp = out1 + r1*1536 + h*64;   // vq slice (cols 0-512 of out1)
    float qf[64];
#pragma unroll
    for (int sg=0; sg<8; sg++){
      u16x8 v = *(const u16x8*)(qp + sg*8);
#pragma unroll
      for (int j=0;j<8;j++) qf[sg*8+j] = b2f(v[j]);
    }
    float sd[5];
#pragma unroll
    for (int t=0;t<5;t++){
      float s = 0.f;
#pragma unroll
      for (int d=0;d<64;d++) s += qf[d]*Ka[t][h][d];
      sd[t] = s*0.125f;
    }
    float mx = sd[0];
#pragma unroll
    for (int t=1;t<5;t++) mx = fmaxf(mx, sd[t]);
    float p[5], ps = 0.f;
#pragma unroll
    for (int t=0;t<5;t++){ p[t] = __expf(sd[t]-mx); ps += p[t]; }
    const float mv = mask[(size_t)bt*3136 + nv] / ps;   // fold mask into normalizer
    u16* op = IN + r1*512 + h*64;
#pragma unroll
    for (int sg=0; sg<8; sg++){
      u16x8 o;
#pragma unroll
      for (int j=0;j<8;j++){
        const int d = sg*8+j;
        float v = 0.f;
#pragma unroll
        for (int t=0;t<5;t++) v += p[t]*Va[t][h][d];
        o[j] = f2b(v*mv);
      }
      *(u16x8*)(op + sg*8) = o;
    }
  } else {
    // combine: 4 (b,h,q) tasks per block, 64 lanes each over d
    const int id = (bid - 3920)*4 + (tid >> 6);   // [0,320)
    const int d = tid & 63;
    const int q = id % 5, t2 = id / 5;
    const int h = t2 & 7, b = t2 >> 3;
    const int bh = b*8 + h;
    float ms = -1e30f;
#pragma unroll
    for (int s2=0;s2<16;s2++) ms = fmaxf(ms, pm[(bh*16+s2)*5+q]);
    float L = 0.f, o = 0.f;
#pragma unroll
    for (int s2=0;s2<16;s2++){
      int base = (bh*16+s2)*5+q;
      float w = __expf(pm[base]-ms);
      L += w*pl[base];
      o += w*pacc[(size_t)base*64 + d];
    }
    IN[(size_t)(b*5+q)*3137*512 + h*64 + d] = f2b(o / L);
  }
}

extern "C" void kernel_launch(void* const* d_in, const int* in_sizes, int n_in,
                              void* d_out, int out_size, void* d_ws, size_t ws_size,
                              hipStream_t stream)
{
  const float* x      = (const float*)d_in[0];
  const float* mask   = (const float*)d_in[1];
  const float* w_vq   = (const float*)d_in[2];
  const float* w_vkv  = (const float*)d_in[3];
  const float* w_aqkv = (const float*)d_in[4];
  const float* w_out  = (const float*)d_in[5];
  const float* b_out  = (const float*)d_in[6];
  float* out = (float*)d_out;
  char* ws = (char*)d_ws;

  constexpr size_t MR = 125480;                          // 40*3137
  constexpr size_t OFF_XB   = 0;                         // M x 512 bf16 (GEMM1 A; later IN)
  constexpr size_t OFF_OUT1 = OFF_XB + MR*512*2;         // M x 1536 bf16 (vq | per-head kv)
  constexpr size_t OFF_W1T  = OFF_OUT1 + MR*1536*2;      // 1536x512 bf16 (permuted cols)
  constexpr size_t OFF_WOT  = OFF_W1T + 1536*512*2;      // 512x512 bf16
  constexpr size_t OFF_AQKV = OFF_WOT + 512*512*2;       // 40x1536 f32
  constexpr size_t OFF_PM   = OFF_AQKV + 40*1536*4;      // 5120 f32
  constexpr size_t OFF_PL   = OFF_PM + 5120*4;           // 5120 f32
  constexpr size_t OFF_PACC = OFF_PL + 5120*4;           // 5120*64 f32

  u16* Xb     = (u16*)(ws + OFF_XB);
  u16* out1   = (u16*)(ws + OFF_OUT1);
  u16* W1T    = (u16*)(ws + OFF_W1T);
  u16* WoutT  = (u16*)(ws + OFF_WOT);
  float* aqkv = (float*)(ws + OFF_AQKV);
  float* pm   = (float*)(ws + OFF_PM);
  float* pl   = (float*)(ws + OFF_PL);
  float* pacc = (float*)(ws + OFF_PACC);

  k_pre<<<6384, 256, 0, stream>>>(x, w_vq, w_vkv, w_out, w_aqkv, Xb, W1T, WoutT, aqkv);
  k_gemm256<0><<<2946, 512, 0, stream>>>(Xb, W1T, (int)MR, 1536, 512, 6,
                                         out1, nullptr, nullptr);
  k_attn_agent<<<1024, 320, 0, stream>>>(out1, aqkv, pm, pl, pacc);
  k_attn_frame<<<4000, 256, 0, stream>>>(out1, aqkv, mask, pm, pl, pacc, Xb);
  k_gemm256<1><<<982, 512, 0, stream>>>(Xb, WoutT, (int)MR, 512, 512, 2,
                                        nullptr, out, b_out);
}